// Round 1
// baseline (643.815 us; speedup 1.0000x reference)
//
#include <hip/hip_runtime.h>
#include <hip/hip_fp16.h>

// Problem constants (fixed by setup_inputs)
#define HW_N 4096   // 64*64 spatial positions
#define C_IN 512    // channels
#define C_Q  64     // query/key channels
#define NB   4      // batch
#define M_Y  640    // Cq + Cq + C stacked output rows
#define LOG2E 1.4426950408889634f

typedef __attribute__((ext_vector_type(8))) short short8;
typedef __attribute__((ext_vector_type(4))) short short4v;
typedef __attribute__((ext_vector_type(4))) float float4v;
typedef unsigned short ushort_t;

__device__ __forceinline__ ushort_t f2h(float x) {
    return __half_as_ushort(__float2half(x));  // RNE
}
__device__ __forceinline__ float h2f(ushort_t h) {
    return __half2float(__ushort_as_half(h));
}
__device__ __forceinline__ void gl2lds16(const ushort_t* g, ushort_t* l) {
    __builtin_amdgcn_global_load_lds(
        (const __attribute__((address_space(1))) unsigned int*)g,
        (__attribute__((address_space(3))) unsigned int*)l, 16, 0, 0);
}

// ---------------------------------------------------------------------------
// split stacked W = [Wq;Wk;Wv] (640x512 fp32) -> fp16 hi/lo (persistent region)
// ---------------------------------------------------------------------------
__global__ __launch_bounds__(256) void split_w(const float* __restrict__ Wq,
                                               const float* __restrict__ Wk,
                                               const float* __restrict__ Wv,
                                               ushort_t* __restrict__ Wh,
                                               ushort_t* __restrict__ Wl) {
    int idx = (blockIdx.x * 256 + threadIdx.x) * 4;
#pragma unroll
    for (int e = 0; e < 4; e++) {
        int i = idx + e;
        int m = i >> 9, k = i & 511;
        float v = (m < C_Q) ? Wq[m * C_IN + k]
                 : (m < 2 * C_Q) ? Wk[(m - C_Q) * C_IN + k]
                 : Wv[(size_t)(m - 2 * C_Q) * C_IN + k];
        ushort_t h = f2h(v);
        Wh[i] = h;
        Wl[i] = f2h(v - h2f(h));
    }
}

// ---------------------------------------------------------------------------
// transpose + split: x [512][4096] fp32 -> xT hi/lo [4096][512] fp16
// Also zeroes D[4096] (rowsum accumulator) in the first 16 blocks of row y==0.
// ---------------------------------------------------------------------------
__global__ __launch_bounds__(256) void split_x(const float* __restrict__ x,
                                               ushort_t* __restrict__ xTh,
                                               ushort_t* __restrict__ xTl,
                                               float* __restrict__ D) {
    if (blockIdx.y == 0 && blockIdx.x < 16) D[blockIdx.x * 256 + threadIdx.x] = 0.f;

    __shared__ float tile[64][65];
    const int n0 = blockIdx.x * 64, k0 = blockIdx.y * 64;
    const int t = threadIdx.x;
#pragma unroll
    for (int it = 0; it < 4; it++) {
        int e = t + it * 256;
        int r = e >> 4, c4 = (e & 15) << 2;
        float4 v = *(const float4*)(x + (size_t)(k0 + r) * HW_N + n0 + c4);
        tile[r][c4 + 0] = v.x; tile[r][c4 + 1] = v.y;
        tile[r][c4 + 2] = v.z; tile[r][c4 + 3] = v.w;
    }
    __syncthreads();
    const int rr = t >> 2, kq = (t & 3) << 4;
    ushort_t h[16], l[16];
#pragma unroll
    for (int j = 0; j < 16; j++) {
        float v = tile[kq + j][rr];
        h[j] = f2h(v);
        l[j] = f2h(v - h2f(h[j]));
    }
    size_t o = (size_t)(n0 + rr) * C_IN + k0 + kq;
    *(uint4*)(xTh + o) = *(uint4*)h;
    *(uint4*)(xTh + o + 8) = *(uint4*)(h + 8);
    *(uint4*)(xTl + o) = *(uint4*)l;
    *(uint4*)(xTl + o + 8) = *(uint4*)(l + 8);
}

// ---------------------------------------------------------------------------
// 3-term fp16 hi/lo GEMM: C[m,n] = sum_k A[m,k]*B[n,k]
// 128x128 block tile, 4 waves, 16x16x32 f16 MFMA.
// EPI 0: Y epilogue (+bias, fp16 h/l; m<128 -> qkT transposed, else V)
// EPI 1: fp32 store (scores) + fused exp-rowsum atomicAdd into Dsum
// ---------------------------------------------------------------------------
template <int EPI>
__global__ __launch_bounds__(256) void mfma3(
    const ushort_t* __restrict__ Ah, const ushort_t* __restrict__ Al, int aStride,
    const ushort_t* __restrict__ Bh, const ushort_t* __restrict__ Bl, int bStride,
    int kLen,
    const float* __restrict__ bq, const float* __restrict__ bk,
    const float* __restrict__ bv,
    ushort_t* __restrict__ qkTh, ushort_t* __restrict__ qkTl,
    ushort_t* __restrict__ Vh, ushort_t* __restrict__ Vl,
    float* __restrict__ outF, float* __restrict__ Dsum) {
    __shared__ ushort_t sAh[128 * 32];
    __shared__ ushort_t sAl[128 * 32];
    __shared__ ushort_t sBh[128 * 32];
    __shared__ ushort_t sBl[128 * 32];

    const int tid = threadIdx.x, w = tid >> 6, lane = tid & 63;
    const int quad = lane >> 4, lr = lane & 15;
    const int m0 = blockIdx.y * 128, n0 = blockIdx.x * 128;

    const ushort_t* src;
    ushort_t* dst;
    int stride, rowBase;
    if (w == 0)      { src = Ah; dst = sAh; stride = aStride; rowBase = m0; }
    else if (w == 1) { src = Al; dst = sAl; stride = aStride; rowBase = m0; }
    else if (w == 2) { src = Bh; dst = sBh; stride = bStride; rowBase = n0; }
    else             { src = Bl; dst = sBl; stride = bStride; rowBase = n0; }
    const int cr = lane >> 2, kp = (lane & 3) << 3;
    const ushort_t* gk = src + (size_t)(rowBase + cr) * stride + kp;

    const int wm = (w & 1) * 64, wn = (w >> 1) * 64;

    float4v acc[4][4];
#pragma unroll
    for (int i = 0; i < 4; i++)
#pragma unroll
        for (int j = 0; j < 4; j++) acc[i][j] = (float4v){0.f, 0.f, 0.f, 0.f};

    for (int kk = 0; kk < kLen; kk += 32) {
#pragma unroll
        for (int c = 0; c < 8; c++)
            gl2lds16(gk + (size_t)(c * 16) * stride + kk, dst + c * 512);
        __syncthreads();

        short8 ah[4], al[4], bh[4], bl[4];
#pragma unroll
        for (int i = 0; i < 4; i++) {
            ah[i] = *(const short8*)&sAh[(wm + i * 16 + lr) * 32 + quad * 8];
            al[i] = *(const short8*)&sAl[(wm + i * 16 + lr) * 32 + quad * 8];
            bh[i] = *(const short8*)&sBh[(wn + i * 16 + lr) * 32 + quad * 8];
            bl[i] = *(const short8*)&sBl[(wn + i * 16 + lr) * 32 + quad * 8];
        }
#pragma unroll
        for (int i = 0; i < 4; i++)
#pragma unroll
            for (int j = 0; j < 4; j++) {
                acc[i][j] = __builtin_amdgcn_mfma_f32_16x16x32_f16(ah[i], bh[j], acc[i][j], 0, 0, 0);
                acc[i][j] = __builtin_amdgcn_mfma_f32_16x16x32_f16(ah[i], bl[j], acc[i][j], 0, 0, 0);
                acc[i][j] = __builtin_amdgcn_mfma_f32_16x16x32_f16(al[i], bh[j], acc[i][j], 0, 0, 0);
            }
        __syncthreads();
    }

    if (EPI == 0) {
#pragma unroll
        for (int i = 0; i < 4; i++)
#pragma unroll
            for (int j = 0; j < 4; j++)
#pragma unroll
                for (int r = 0; r < 4; r++) {
                    const int m = m0 + wm + i * 16 + quad * 4 + r;
                    const int n = n0 + wn + j * 16 + lr;
                    float bi = (m < C_Q) ? bq[m]
                              : (m < 2 * C_Q) ? bk[m - C_Q] : bv[m - 2 * C_Q];
                    float v = acc[i][j][r] + bi;
                    ushort_t h = f2h(v);
                    ushort_t lo = f2h(v - h2f(h));
                    if (m < 2 * C_Q) {
                        qkTh[(size_t)n * (2 * C_Q) + m] = h;
                        qkTl[(size_t)n * (2 * C_Q) + m] = lo;
                    } else {
                        Vh[(size_t)(m - 2 * C_Q) * HW_N + n] = h;
                        Vl[(size_t)(m - 2 * C_Q) * HW_N + n] = lo;
                    }
                }
    } else {
        // store S + fused per-row exp-sum partials
#pragma unroll
        for (int i = 0; i < 4; i++) {
#pragma unroll
            for (int r = 0; r < 4; r++) {
                float s = 0.f;
#pragma unroll
                for (int j = 0; j < 4; j++) {
                    const int m = m0 + wm + i * 16 + quad * 4 + r;
                    const int n = n0 + wn + j * 16 + lr;
                    outF[(size_t)m * HW_N + n] = acc[i][j][r];
                    s += __expf(acc[i][j][r]);
                }
                s += __shfl_xor(s, 1);
                s += __shfl_xor(s, 2);
                s += __shfl_xor(s, 4);
                s += __shfl_xor(s, 8);
                if (lr == 0)
                    atomicAdd(&Dsum[m0 + wm + i * 16 + quad * 4 + r], s);
            }
        }
    }
}

// ---------------------------------------------------------------------------
// feat GEMM, software-pipelined: res[m,n] = sum_k (Vh+Vl)[m,k] * P[n,k],
//   P[n,k] = f16( exp2(S[n,k]*log2e - log2 D[n]) )
// v2 geometry: 256x128 block tile, 4 waves each owning a 64m x 128n wave-tile
// (acc[4][8]).  Rationale: the old 64x64 wave-tile read 384 B of LDS per MFMA
// (> the ~256-320 B/MFMA LDS port budget) -> LDS-issue bound (MfmaUtil 26%).
// 64x128 cuts that to 256 B/MFMA, and halves per-MFMA barrier + S->P exp cost.
// Same single-barrier double-buffered pipeline as before (structure unchanged,
// only scaled): issues for iter k+1 go out AFTER the barrier of iter k.
// grid (32, 2, 4) = 256 blocks, 1 block/CU (80 KB LDS), z=4 parts unchanged.
// ---------------------------------------------------------------------------
__global__ __launch_bounds__(256) void feat5(const ushort_t* __restrict__ Vh,
                                             const ushort_t* __restrict__ Vl,
                                             const float* __restrict__ S,
                                             const float* __restrict__ D,
                                             float* __restrict__ out,
                                             float* __restrict__ part,
                                             int kLen) {
    __shared__ ushort_t sVh[2][256 * 32];
    __shared__ ushort_t sVl[2][256 * 32];
    __shared__ ushort_t sP [2][128 * 32];

    const int tid = threadIdx.x, w = tid >> 6, lane = tid & 63;
    const int quad = lane >> 4, lr = lane & 15;
    const int m0 = blockIdx.y * 256, n0 = blockIdx.x * 128;
    const int k0 = blockIdx.z * kLen;

    // V staging: waves 0-1 stage Vh rows (w&1)*128..+127, waves 2-3 ditto Vl.
    // 8 chunks of 16 rows per wave per k-step; global col pre-swizzled so the
    // linear global_load_lds destination yields the swizzled LDS layout.
    const int crv = lane >> 2, uv = lane & 3;
    const int vcol = (uv ^ ((crv >> 1) & 3)) << 3;   // swizzled 16B unit
    const ushort_t* vbase = (w < 2) ? Vh : Vl;
    const ushort_t* gV = vbase + (size_t)(m0 + (w & 1) * 128 + crv) * HW_N + vcol + k0;
    const int so0 = (w & 1) * (128 * 32);

    // S prefetch geometry: thread owns rows pr+32c (c=0..3), 4-float unit pu
    const int pr = tid >> 3, pu = tid & 7;
    const float* gS = S + (size_t)(n0 + pr) * HW_N + k0 + pu * 4;
    const int pphys = (pu ^ (pr & 7)) << 2;
    float lrw[4];
#pragma unroll
    for (int c = 0; c < 4; c++) lrw[c] = -log2f(D[n0 + pr + 32 * c]);

    const int wm = w * 64;   // wave's 64-row m-strip within the 256-row tile

    float4 sreg[4];
    // prologue: stage V(0) into buf0, load S(0) into regs
    {
        ushort_t* db = ((w < 2) ? sVh : sVl)[0] + so0;
#pragma unroll
        for (int c = 0; c < 8; c++) gl2lds16(gV + (size_t)(c * 16) * HW_N, db + c * 512);
#pragma unroll
        for (int c = 0; c < 4; c++)
            sreg[c] = *(const float4*)(gS + (size_t)(32 * c) * HW_N);
    }
    __syncthreads();  // V(0)+S(0) drained

    float4v acc[4][8];
#pragma unroll
    for (int i = 0; i < 4; i++)
#pragma unroll
        for (int j = 0; j < 8; j++) acc[i][j] = (float4v){0.f, 0.f, 0.f, 0.f};

    const int nIter = kLen >> 5;
    for (int it = 0; it < nIter; ++it) {
        const int kk = it << 5;
        const int cur = it & 1, nxt = cur ^ 1;

        // convert S(it) regs -> sP[cur]
#pragma unroll
        for (int c = 0; c < 4; c++) {
            ushort_t h4[4];
            h4[0] = f2h(exp2f(fmaf(sreg[c].x, LOG2E, lrw[c])));
            h4[1] = f2h(exp2f(fmaf(sreg[c].y, LOG2E, lrw[c])));
            h4[2] = f2h(exp2f(fmaf(sreg[c].z, LOG2E, lrw[c])));
            h4[3] = f2h(exp2f(fmaf(sreg[c].w, LOG2E, lrw[c])));
            *(short4v*)&sP[cur][(pr + 32 * c) * 32 + pphys] = *(short4v*)h4;
        }
        __syncthreads();  // sP[cur] visible; V(it) (in flight a full iter) drained

        // issue next iteration's loads — they fly during this MFMA section
        if (it + 1 < nIter) {
            ushort_t* db = ((w < 2) ? sVh : sVl)[nxt] + so0;
#pragma unroll
            for (int c = 0; c < 8; c++)
                gl2lds16(gV + (size_t)(c * 16) * HW_N + kk + 32, db + c * 512);
#pragma unroll
            for (int c = 0; c < 4; c++)
                sreg[c] = *(const float4*)(gS + (size_t)(32 * c) * HW_N + kk + 32);
        }

        // B fragments: one read, reused by all 4 i and both hi/lo terms
        short8 bh[8];
#pragma unroll
        for (int j = 0; j < 8; j++) {
            const int row = j * 16 + lr;
            const int p0 = (((2 * quad)     ^ (lr & 7)) << 2);
            const int p1 = (((2 * quad + 1) ^ (lr & 7)) << 2);
            short4v x0 = *(const short4v*)&sP[cur][row * 32 + p0];
            short4v x1 = *(const short4v*)&sP[cur][row * 32 + p1];
            bh[j] = (short8){x0[0], x0[1], x0[2], x0[3], x1[0], x1[1], x1[2], x1[3]};
        }
#pragma unroll
        for (int i = 0; i < 4; i++) {
            const int row = wm + i * 16 + lr;
            const int up = (quad ^ ((lr >> 1) & 3)) << 3;
            short8 ah = *(const short8*)&sVh[cur][row * 32 + up];
            short8 al = *(const short8*)&sVl[cur][row * 32 + up];
#pragma unroll
            for (int j = 0; j < 8; j++) {
                acc[i][j] = __builtin_amdgcn_mfma_f32_16x16x32_f16(ah, bh[j], acc[i][j], 0, 0, 0);
                acc[i][j] = __builtin_amdgcn_mfma_f32_16x16x32_f16(al, bh[j], acc[i][j], 0, 0, 0);
            }
        }
        // no trailing barrier: buffer parity + next barrier's drains cover WAR
    }

    float* o = (blockIdx.z == 0) ? out
             : (part + (size_t)(blockIdx.z - 1) * ((size_t)C_IN * HW_N));
#pragma unroll
    for (int i = 0; i < 4; i++)
#pragma unroll
        for (int j = 0; j < 8; j++)
#pragma unroll
            for (int r = 0; r < 4; r++) {
                const int m = m0 + wm + i * 16 + quad * 4 + r;
                const int n = n0 + j * 16 + lr;
                o[(size_t)m * HW_N + n] = acc[i][j][r];
            }
}

// out = alpha * (out + p0 + p1 + p2), float4-vectorized
__global__ __launch_bounds__(256) void reduce_alpha3(float* __restrict__ out,
                                                     const float4* __restrict__ part,
                                                     size_t stride4,
                                                     const float* __restrict__ alpha) {
    const size_t i = (size_t)blockIdx.x * 256 + threadIdx.x;
    const float a = alpha[0];
    float4* out4 = (float4*)out;
    float4 s = out4[i];
    float4 p0 = part[i];
    float4 p1 = part[i + stride4];
    float4 p2 = part[i + 2 * stride4];
    float4 o;
    o.x = a * (s.x + p0.x + p1.x + p2.x);
    o.y = a * (s.y + p0.y + p1.y + p2.y);
    o.z = a * (s.z + p0.z + p1.z + p2.z);
    o.w = a * (s.w + p0.w + p1.w + p2.w);
    out4[i] = o;
}

// ---------------------------------------------------------------------------

extern "C" void kernel_launch(void* const* d_in, const int* in_sizes, int n_in,
                              void* d_out, int out_size, void* d_ws, size_t ws_size,
                              hipStream_t stream) {
    const float* x     = (const float*)d_in[0];
    const float* Wq    = (const float*)d_in[1];
    const float* bq    = (const float*)d_in[2];
    const float* Wk    = (const float*)d_in[3];
    const float* bk    = (const float*)d_in[4];
    const float* Wv    = (const float*)d_in[5];
    const float* bv    = (const float*)d_in[6];
    const float* alpha = (const float*)d_in[7];
    float* out = (float*)d_out;

    // ws layout (persistent region first — nothing here is overlaid):
    //   D         : 4096 fp32 rowsum               (16 KB)
    //   qkTh/qkTl : 4096 x 128 fp16 each           (2.0 MB)
    //   Vh/Vl     : 512 x 4096 fp16 each           (8.0 MB)
    //   Wh/Wl     : 640 x 512 fp16 each            (1.3 MB)
    //   scores    : 4096 x 4096 fp32               (67.1 MB)
    //     overlay (dead before scores written): xTh/xTl (8.4 MB)
    //   part      : 3 x 512 x 4096 fp32            (25.2 MB)  [z=1..3 partials]
    float* D = (float*)d_ws;
    ushort_t* qkTh = (ushort_t*)(D + HW_N);
    ushort_t* qkTl = qkTh + (size_t)HW_N * 2 * C_Q;
    ushort_t* Vh   = qkTl + (size_t)HW_N * 2 * C_Q;
    ushort_t* Vl   = Vh + (size_t)C_IN * HW_N;
    ushort_t* Wh   = Vl + (size_t)C_IN * HW_N;
    ushort_t* Wl   = Wh + (size_t)M_Y * C_IN;
    float* scores  = (float*)(Wl + (size_t)M_Y * C_IN);
    float* part    = scores + (size_t)HW_N * HW_N;

    ushort_t* xTh = (ushort_t*)scores;
    ushort_t* xTl = xTh + (size_t)HW_N * C_IN;

    split_w<<<dim3(M_Y * C_IN / 4 / 256), dim3(256), 0, stream>>>(Wq, Wk, Wv, Wh, Wl);

    for (int b = 0; b < NB; b++) {
        const float* xb = x + (size_t)b * C_IN * HW_N;
        float* outb = out + (size_t)b * C_IN * HW_N;

        split_x<<<dim3(HW_N / 64, C_IN / 64), dim3(256), 0, stream>>>(xb, xTh, xTl, D);

        // Y = W*x + b -> qkT (transposed, m<128) and V (m>=128), fp16 h/l
        mfma3<0><<<dim3(HW_N / 128, M_Y / 128), dim3(256), 0, stream>>>(
            Wh, Wl, C_IN, xTh, xTl, C_IN, C_IN,
            bq, bk, bv, qkTh, qkTl, Vh, Vl, nullptr, nullptr);

        // S[i,j] = sum_c q[c,i]k[c,j]  (fp32) + fused exp-rowsum into D
        mfma3<1><<<dim3(HW_N / 128, HW_N / 128), dim3(256), 0, stream>>>(
            qkTh, qkTl, 2 * C_Q, qkTh + C_Q, qkTl + C_Q, 2 * C_Q, C_Q,
            nullptr, nullptr, nullptr, nullptr, nullptr, nullptr, nullptr,
            scores, D);

        // res[c,i] = sum_j (Vh+Vl)[c,j] * f16(exp(S[i,j])/D[i]); z=0->out, z>0->part
        feat5<<<dim3(HW_N / 128, 2, 4), dim3(256), 0, stream>>>(
            Vh, Vl, scores, D, outb, part, HW_N / 4);

        // out = alpha * (out + part0 + part1 + part2)
        reduce_alpha3<<<dim3((C_IN * HW_N / 4) / 256), dim3(256), 0, stream>>>(
            outb, (const float4*)part, (size_t)C_IN * HW_N / 4, alpha);
    }
}

// Round 2
// 620.935 us; speedup vs baseline: 1.0368x; 1.0368x over previous
//
#include <hip/hip_runtime.h>
#include <hip/hip_fp16.h>

// Problem constants (fixed by setup_inputs)
#define HW_N 4096   // 64*64 spatial positions
#define C_IN 512    // channels
#define C_Q  64     // query/key channels
#define NB   4      // batch
#define M_Y  640    // Cq + Cq + C stacked output rows
#define LOG2E 1.4426950408889634f

typedef __attribute__((ext_vector_type(8))) short short8;
typedef __attribute__((ext_vector_type(4))) short short4v;
typedef __attribute__((ext_vector_type(4))) float float4v;
typedef unsigned short ushort_t;

__device__ __forceinline__ ushort_t f2h(float x) {
    return __half_as_ushort(__float2half(x));  // RNE
}
__device__ __forceinline__ float h2f(ushort_t h) {
    return __half2float(__ushort_as_half(h));
}
__device__ __forceinline__ void gl2lds16(const ushort_t* g, ushort_t* l) {
    __builtin_amdgcn_global_load_lds(
        (const __attribute__((address_space(1))) unsigned int*)g,
        (__attribute__((address_space(3))) unsigned int*)l, 16, 0, 0);
}

// ---------------------------------------------------------------------------
// split stacked W = [Wq;Wk;Wv] (640x512 fp32) -> fp16 hi/lo (persistent region)
// ---------------------------------------------------------------------------
__global__ __launch_bounds__(256) void split_w(const float* __restrict__ Wq,
                                               const float* __restrict__ Wk,
                                               const float* __restrict__ Wv,
                                               ushort_t* __restrict__ Wh,
                                               ushort_t* __restrict__ Wl) {
    int idx = (blockIdx.x * 256 + threadIdx.x) * 4;
#pragma unroll
    for (int e = 0; e < 4; e++) {
        int i = idx + e;
        int m = i >> 9, k = i & 511;
        float v = (m < C_Q) ? Wq[m * C_IN + k]
                 : (m < 2 * C_Q) ? Wk[(m - C_Q) * C_IN + k]
                 : Wv[(size_t)(m - 2 * C_Q) * C_IN + k];
        ushort_t h = f2h(v);
        Wh[i] = h;
        Wl[i] = f2h(v - h2f(h));
    }
}

// ---------------------------------------------------------------------------
// transpose + split: x [512][4096] fp32 -> xT hi/lo [4096][512] fp16
// Also zeroes D[4096] (rowsum accumulator) in the first 16 blocks of row y==0.
// ---------------------------------------------------------------------------
__global__ __launch_bounds__(256) void split_x(const float* __restrict__ x,
                                               ushort_t* __restrict__ xTh,
                                               ushort_t* __restrict__ xTl,
                                               float* __restrict__ D) {
    if (blockIdx.y == 0 && blockIdx.x < 16) D[blockIdx.x * 256 + threadIdx.x] = 0.f;

    __shared__ float tile[64][65];
    const int n0 = blockIdx.x * 64, k0 = blockIdx.y * 64;
    const int t = threadIdx.x;
#pragma unroll
    for (int it = 0; it < 4; it++) {
        int e = t + it * 256;
        int r = e >> 4, c4 = (e & 15) << 2;
        float4 v = *(const float4*)(x + (size_t)(k0 + r) * HW_N + n0 + c4);
        tile[r][c4 + 0] = v.x; tile[r][c4 + 1] = v.y;
        tile[r][c4 + 2] = v.z; tile[r][c4 + 3] = v.w;
    }
    __syncthreads();
    const int rr = t >> 2, kq = (t & 3) << 4;
    ushort_t h[16], l[16];
#pragma unroll
    for (int j = 0; j < 16; j++) {
        float v = tile[kq + j][rr];
        h[j] = f2h(v);
        l[j] = f2h(v - h2f(h[j]));
    }
    size_t o = (size_t)(n0 + rr) * C_IN + k0 + kq;
    *(uint4*)(xTh + o) = *(uint4*)h;
    *(uint4*)(xTh + o + 8) = *(uint4*)(h + 8);
    *(uint4*)(xTl + o) = *(uint4*)l;
    *(uint4*)(xTl + o + 8) = *(uint4*)(l + 8);
}

// ---------------------------------------------------------------------------
// 3-term fp16 hi/lo GEMM: C[m,n] = sum_k A[m,k]*B[n,k]
// 128x128 block tile, 4 waves, 16x16x32 f16 MFMA.
// EPI 0: Y epilogue (+bias, fp16 h/l; m<128 -> qkT transposed, else V)
// EPI 1: fp32 store (scores) + fused exp-rowsum atomicAdd into Dsum
// ---------------------------------------------------------------------------
template <int EPI>
__global__ __launch_bounds__(256) void mfma3(
    const ushort_t* __restrict__ Ah, const ushort_t* __restrict__ Al, int aStride,
    const ushort_t* __restrict__ Bh, const ushort_t* __restrict__ Bl, int bStride,
    int kLen,
    const float* __restrict__ bq, const float* __restrict__ bk,
    const float* __restrict__ bv,
    ushort_t* __restrict__ qkTh, ushort_t* __restrict__ qkTl,
    ushort_t* __restrict__ Vh, ushort_t* __restrict__ Vl,
    float* __restrict__ outF, float* __restrict__ Dsum) {
    __shared__ ushort_t sAh[128 * 32];
    __shared__ ushort_t sAl[128 * 32];
    __shared__ ushort_t sBh[128 * 32];
    __shared__ ushort_t sBl[128 * 32];

    const int tid = threadIdx.x, w = tid >> 6, lane = tid & 63;
    const int quad = lane >> 4, lr = lane & 15;
    const int m0 = blockIdx.y * 128, n0 = blockIdx.x * 128;

    const ushort_t* src;
    ushort_t* dst;
    int stride, rowBase;
    if (w == 0)      { src = Ah; dst = sAh; stride = aStride; rowBase = m0; }
    else if (w == 1) { src = Al; dst = sAl; stride = aStride; rowBase = m0; }
    else if (w == 2) { src = Bh; dst = sBh; stride = bStride; rowBase = n0; }
    else             { src = Bl; dst = sBl; stride = bStride; rowBase = n0; }
    const int cr = lane >> 2, kp = (lane & 3) << 3;
    const ushort_t* gk = src + (size_t)(rowBase + cr) * stride + kp;

    const int wm = (w & 1) * 64, wn = (w >> 1) * 64;

    float4v acc[4][4];
#pragma unroll
    for (int i = 0; i < 4; i++)
#pragma unroll
        for (int j = 0; j < 4; j++) acc[i][j] = (float4v){0.f, 0.f, 0.f, 0.f};

    for (int kk = 0; kk < kLen; kk += 32) {
#pragma unroll
        for (int c = 0; c < 8; c++)
            gl2lds16(gk + (size_t)(c * 16) * stride + kk, dst + c * 512);
        __syncthreads();

        short8 ah[4], al[4], bh[4], bl[4];
#pragma unroll
        for (int i = 0; i < 4; i++) {
            ah[i] = *(const short8*)&sAh[(wm + i * 16 + lr) * 32 + quad * 8];
            al[i] = *(const short8*)&sAl[(wm + i * 16 + lr) * 32 + quad * 8];
            bh[i] = *(const short8*)&sBh[(wn + i * 16 + lr) * 32 + quad * 8];
            bl[i] = *(const short8*)&sBl[(wn + i * 16 + lr) * 32 + quad * 8];
        }
#pragma unroll
        for (int i = 0; i < 4; i++)
#pragma unroll
            for (int j = 0; j < 4; j++) {
                acc[i][j] = __builtin_amdgcn_mfma_f32_16x16x32_f16(ah[i], bh[j], acc[i][j], 0, 0, 0);
                acc[i][j] = __builtin_amdgcn_mfma_f32_16x16x32_f16(ah[i], bl[j], acc[i][j], 0, 0, 0);
                acc[i][j] = __builtin_amdgcn_mfma_f32_16x16x32_f16(al[i], bh[j], acc[i][j], 0, 0, 0);
            }
        __syncthreads();
    }

    if (EPI == 0) {
#pragma unroll
        for (int i = 0; i < 4; i++)
#pragma unroll
            for (int j = 0; j < 4; j++)
#pragma unroll
                for (int r = 0; r < 4; r++) {
                    const int m = m0 + wm + i * 16 + quad * 4 + r;
                    const int n = n0 + wn + j * 16 + lr;
                    float bi = (m < C_Q) ? bq[m]
                              : (m < 2 * C_Q) ? bk[m - C_Q] : bv[m - 2 * C_Q];
                    float v = acc[i][j][r] + bi;
                    ushort_t h = f2h(v);
                    ushort_t lo = f2h(v - h2f(h));
                    if (m < 2 * C_Q) {
                        qkTh[(size_t)n * (2 * C_Q) + m] = h;
                        qkTl[(size_t)n * (2 * C_Q) + m] = lo;
                    } else {
                        Vh[(size_t)(m - 2 * C_Q) * HW_N + n] = h;
                        Vl[(size_t)(m - 2 * C_Q) * HW_N + n] = lo;
                    }
                }
    } else {
        // store S + fused per-row exp-sum partials
#pragma unroll
        for (int i = 0; i < 4; i++) {
#pragma unroll
            for (int r = 0; r < 4; r++) {
                float s = 0.f;
#pragma unroll
                for (int j = 0; j < 4; j++) {
                    const int m = m0 + wm + i * 16 + quad * 4 + r;
                    const int n = n0 + wn + j * 16 + lr;
                    outF[(size_t)m * HW_N + n] = acc[i][j][r];
                    s += __expf(acc[i][j][r]);
                }
                s += __shfl_xor(s, 1);
                s += __shfl_xor(s, 2);
                s += __shfl_xor(s, 4);
                s += __shfl_xor(s, 8);
                if (lr == 0)
                    atomicAdd(&Dsum[m0 + wm + i * 16 + quad * 4 + r], s);
            }
        }
    }
}

// ---------------------------------------------------------------------------
// feat GEMM v3: res[m,n] = sum_k (Vh+Vl)[m,k] * P[n,k],
//   P[n,k] = f16( exp2(S[n,k]*log2e - log2 D[n]) )
// Geometry: 128m x 256n block tile, 4 waves (2m x 2n), wave-tile 64x128
// (acc[4][8]).  256 B of LDS fragment reads per MFMA (vs 384 at 64x64) and
// half the per-MFMA exp/barrier cost.  LDS = 64 KB -> 2 blocks/CU; grid must
// supply 512 blocks for that, hence z=8 (k-split into 8 partials).  Round-1
// lesson: this wave-tile at z=4 gives only 1024 waves for 2048 slots -> 1
// wave/SIMD -> full serialization; z=8 restores 2 waves/SIMD.
// sP is written with the same 16B-unit XOR swizzle as V, so each B fragment
// is ONE ds_read_b128 (round-0 used 2x b64 + pack).  MFMA terms ordered
// all-ah-then-all-al to break same-acc back-to-back dependencies.
// Single-barrier double-buffered pipeline identical to round-0.
// ---------------------------------------------------------------------------
__global__ __launch_bounds__(256, 2) void feat6(const ushort_t* __restrict__ Vh,
                                                const ushort_t* __restrict__ Vl,
                                                const float* __restrict__ S,
                                                const float* __restrict__ D,
                                                float* __restrict__ out,
                                                float* __restrict__ part,
                                                int kLen) {
    __shared__ ushort_t sVh[2][128 * 32];
    __shared__ ushort_t sVl[2][128 * 32];
    __shared__ ushort_t sP [2][256 * 32];

    const int tid = threadIdx.x, w = tid >> 6, lane = tid & 63;
    const int quad = lane >> 4, lr = lane & 15;
    const int m0 = blockIdx.y * 128, n0 = blockIdx.x * 256;
    const int k0 = blockIdx.z * kLen;

    // V staging (round-0 scheme, unchanged): waves 0-1 -> Vh, waves 2-3 -> Vl,
    // 4 chunks of 16 rows each; swizzled global col, linear LDS dest.
    const int crv = lane >> 2, uv = lane & 3;
    const int vcol = (uv ^ ((crv >> 1) & 3)) << 3;   // swizzled 16B unit
    const ushort_t* vbase = (w < 2) ? Vh : Vl;
    const ushort_t* gVsrc[4];
    int sOfs[4];
#pragma unroll
    for (int c = 0; c < 4; c++) {
        const int chunk = ((w & 1) * 4 + c);         // 0..7 within h or l
        gVsrc[c] = vbase + (size_t)(m0 + chunk * 16 + crv) * HW_N + vcol + k0;
        sOfs[c] = chunk * 512;
    }

    // S prefetch: thread owns rows pr+32c (c=0..7), 4-float k-unit pu.
    // Write target uses the same 16B-unit XOR swizzle as V so the read side
    // is a single ds_read_b128.  (row>>1)&3 == (pr>>1)&3 since 32c keeps
    // bits 1-2.
    const int pr = tid >> 3, pu = tid & 7;
    const float* gS = S + (size_t)(n0 + pr) * HW_N + k0 + pu * 4;
    const int pdst = (((pu >> 1) ^ ((pr >> 1) & 3)) << 3) + ((pu & 1) << 2);
    float lrw[8];
#pragma unroll
    for (int c = 0; c < 8; c++) lrw[c] = -log2f(D[n0 + pr + 32 * c]);

    const int wm = (w & 1) * 64, wn = (w >> 1) * 128;

    float4 sreg[8];
    // prologue: stage V(0) into buf0, load S(0) into regs
    {
        ushort_t* db = ((w < 2) ? sVh : sVl)[0];
#pragma unroll
        for (int c = 0; c < 4; c++) gl2lds16(gVsrc[c], db + sOfs[c]);
#pragma unroll
        for (int c = 0; c < 8; c++)
            sreg[c] = *(const float4*)(gS + (size_t)(32 * c) * HW_N);
    }
    __syncthreads();  // V(0)+S(0) drained

    float4v acc[4][8];
#pragma unroll
    for (int i = 0; i < 4; i++)
#pragma unroll
        for (int j = 0; j < 8; j++) acc[i][j] = (float4v){0.f, 0.f, 0.f, 0.f};

    const int nIter = kLen >> 5;
    for (int it = 0; it < nIter; ++it) {
        const int kk = it << 5;
        const int cur = it & 1, nxt = cur ^ 1;

        // convert S(it) regs -> sP[cur] (swizzled 8B ds_writes)
#pragma unroll
        for (int c = 0; c < 8; c++) {
            ushort_t h4[4];
            h4[0] = f2h(exp2f(fmaf(sreg[c].x, LOG2E, lrw[c])));
            h4[1] = f2h(exp2f(fmaf(sreg[c].y, LOG2E, lrw[c])));
            h4[2] = f2h(exp2f(fmaf(sreg[c].z, LOG2E, lrw[c])));
            h4[3] = f2h(exp2f(fmaf(sreg[c].w, LOG2E, lrw[c])));
            *(short4v*)&sP[cur][(pr + 32 * c) * 32 + pdst] = *(short4v*)h4;
        }
        __syncthreads();  // sP[cur] visible; V(it) (in flight a full iter) drained

        // issue next iteration's loads — they fly during this MFMA section
        if (it + 1 < nIter) {
            ushort_t* db = ((w < 2) ? sVh : sVl)[nxt];
#pragma unroll
            for (int c = 0; c < 4; c++) gl2lds16(gVsrc[c] + kk + 32, db + sOfs[c]);
#pragma unroll
            for (int c = 0; c < 8; c++)
                sreg[c] = *(const float4*)(gS + (size_t)(32 * c) * HW_N + kk + 32);
        }

        // B fragments: single b128 each (swizzle matches sP write)
        short8 bh[8];
#pragma unroll
        for (int j = 0; j < 8; j++) {
            const int row = wn + j * 16 + lr;
            bh[j] = *(const short8*)&sP[cur][row * 32 + ((quad ^ ((lr >> 1) & 3)) << 3)];
        }
#pragma unroll
        for (int i = 0; i < 4; i++) {
            const int row = wm + i * 16 + lr;
            const int up = (quad ^ ((lr >> 1) & 3)) << 3;
            short8 ah = *(const short8*)&sVh[cur][row * 32 + up];
            short8 al = *(const short8*)&sVl[cur][row * 32 + up];
#pragma unroll
            for (int j = 0; j < 8; j++)
                acc[i][j] = __builtin_amdgcn_mfma_f32_16x16x32_f16(ah, bh[j], acc[i][j], 0, 0, 0);
#pragma unroll
            for (int j = 0; j < 8; j++)
                acc[i][j] = __builtin_amdgcn_mfma_f32_16x16x32_f16(al, bh[j], acc[i][j], 0, 0, 0);
        }
        // no trailing barrier: buffer parity + next barrier's drains cover WAR
    }

    float* o = (blockIdx.z == 0) ? out
             : (part + (size_t)(blockIdx.z - 1) * ((size_t)C_IN * HW_N));
#pragma unroll
    for (int i = 0; i < 4; i++)
#pragma unroll
        for (int j = 0; j < 8; j++)
#pragma unroll
            for (int r = 0; r < 4; r++) {
                const int m = m0 + wm + i * 16 + quad * 4 + r;
                const int n = n0 + wn + j * 16 + lr;
                o[(size_t)m * HW_N + n] = acc[i][j][r];
            }
}

// out = alpha * (out + sum of np partials), float4-vectorized
__global__ __launch_bounds__(256) void reduce_alphaN(float* __restrict__ out,
                                                     const float4* __restrict__ part,
                                                     size_t stride4,
                                                     const float* __restrict__ alpha,
                                                     int np) {
    const size_t i = (size_t)blockIdx.x * 256 + threadIdx.x;
    const float a = alpha[0];
    float4* out4 = (float4*)out;
    float4 s = out4[i];
    for (int p = 0; p < np; p++) {
        float4 t = part[i + (size_t)p * stride4];
        s.x += t.x; s.y += t.y; s.z += t.z; s.w += t.w;
    }
    float4 o;
    o.x = a * s.x; o.y = a * s.y; o.z = a * s.z; o.w = a * s.w;
    out4[i] = o;
}

// ---------------------------------------------------------------------------

extern "C" void kernel_launch(void* const* d_in, const int* in_sizes, int n_in,
                              void* d_out, int out_size, void* d_ws, size_t ws_size,
                              hipStream_t stream) {
    const float* x     = (const float*)d_in[0];
    const float* Wq    = (const float*)d_in[1];
    const float* bq    = (const float*)d_in[2];
    const float* Wk    = (const float*)d_in[3];
    const float* bk    = (const float*)d_in[4];
    const float* Wv    = (const float*)d_in[5];
    const float* bv    = (const float*)d_in[6];
    const float* alpha = (const float*)d_in[7];
    float* out = (float*)d_out;

    // ws layout (persistent region first — nothing here is overlaid):
    //   D         : 4096 fp32 rowsum               (16 KB)
    //   qkTh/qkTl : 4096 x 128 fp16 each           (2.0 MB)
    //   Vh/Vl     : 512 x 4096 fp16 each           (8.0 MB)
    //   Wh/Wl     : 640 x 512 fp16 each            (1.3 MB)
    //   scores    : 4096 x 4096 fp32               (67.1 MB)
    //     overlay (dead before scores written): xTh/xTl (8.4 MB)
    //   part      : (zsplit-1) x 512 x 4096 fp32   (58.7 MB at z=8)
    float* D = (float*)d_ws;
    ushort_t* qkTh = (ushort_t*)(D + HW_N);
    ushort_t* qkTl = qkTh + (size_t)HW_N * 2 * C_Q;
    ushort_t* Vh   = qkTl + (size_t)HW_N * 2 * C_Q;
    ushort_t* Vl   = Vh + (size_t)C_IN * HW_N;
    ushort_t* Wh   = Vl + (size_t)C_IN * HW_N;
    ushort_t* Wl   = Wh + (size_t)M_Y * C_IN;
    float* scores  = (float*)(Wl + (size_t)M_Y * C_IN);
    float* part    = scores + (size_t)HW_N * HW_N;

    ushort_t* xTh = (ushort_t*)scores;
    ushort_t* xTl = xTh + (size_t)HW_N * C_IN;

    // z-split: 8 needs 7 partial planes; fall back to 4 (correct, slower) if
    // the workspace can't hold them.
    const size_t planeF = (size_t)C_IN * HW_N;
    const size_t baseF  = (size_t)(part - (float*)d_ws);
    const int zsplit = (ws_size >= (baseF + 7 * planeF) * sizeof(float)) ? 8 : 4;

    split_w<<<dim3(M_Y * C_IN / 4 / 256), dim3(256), 0, stream>>>(Wq, Wk, Wv, Wh, Wl);

    for (int b = 0; b < NB; b++) {
        const float* xb = x + (size_t)b * C_IN * HW_N;
        float* outb = out + (size_t)b * C_IN * HW_N;

        split_x<<<dim3(HW_N / 64, C_IN / 64), dim3(256), 0, stream>>>(xb, xTh, xTl, D);

        // Y = W*x + b -> qkT (transposed, m<128) and V (m>=128), fp16 h/l
        mfma3<0><<<dim3(HW_N / 128, M_Y / 128), dim3(256), 0, stream>>>(
            Wh, Wl, C_IN, xTh, xTl, C_IN, C_IN,
            bq, bk, bv, qkTh, qkTl, Vh, Vl, nullptr, nullptr);

        // S[i,j] = sum_c q[c,i]k[c,j]  (fp32) + fused exp-rowsum into D
        mfma3<1><<<dim3(HW_N / 128, HW_N / 128), dim3(256), 0, stream>>>(
            qkTh, qkTl, 2 * C_Q, qkTh + C_Q, qkTl + C_Q, 2 * C_Q, C_Q,
            nullptr, nullptr, nullptr, nullptr, nullptr, nullptr, nullptr,
            scores, D);

        // res[c,i] = sum_j (Vh+Vl)[c,j] * f16(exp(S[i,j])/D[i]); z=0->out, z>0->part
        feat6<<<dim3(HW_N / 256, C_IN / 128, zsplit), dim3(256), 0, stream>>>(
            Vh, Vl, scores, D, outb, part, HW_N / zsplit);

        // out = alpha * (out + sum parts)
        reduce_alphaN<<<dim3((C_IN * HW_N / 4) / 256), dim3(256), 0, stream>>>(
            outb, (const float4*)part, (size_t)C_IN * HW_N / 4, alpha, zsplit - 1);
    }
}

// Round 3
// 600.813 us; speedup vs baseline: 1.0716x; 1.0335x over previous
//
#include <hip/hip_runtime.h>
#include <hip/hip_fp16.h>

// Problem constants (fixed by setup_inputs)
#define HW_N 4096   // 64*64 spatial positions
#define C_IN 512    // channels
#define C_Q  64     // query/key channels
#define NB   4      // batch
#define M_Y  640    // Cq + Cq + C stacked output rows
#define LOG2E 1.4426950408889634f

typedef __attribute__((ext_vector_type(8))) short short8;
typedef __attribute__((ext_vector_type(4))) short short4v;
typedef __attribute__((ext_vector_type(4))) float float4v;
typedef unsigned short ushort_t;

__device__ __forceinline__ ushort_t f2h(float x) {
    return __half_as_ushort(__float2half(x));  // RNE
}
__device__ __forceinline__ float h2f(ushort_t h) {
    return __half2float(__ushort_as_half(h));
}
__device__ __forceinline__ void gl2lds16(const ushort_t* g, ushort_t* l) {
    __builtin_amdgcn_global_load_lds(
        (const __attribute__((address_space(1))) unsigned int*)g,
        (__attribute__((address_space(3))) unsigned int*)l, 16, 0, 0);
}

// ---------------------------------------------------------------------------
// split stacked W = [Wq;Wk;Wv] (640x512 fp32) -> fp16 hi/lo (persistent region)
// ---------------------------------------------------------------------------
__global__ __launch_bounds__(256) void split_w(const float* __restrict__ Wq,
                                               const float* __restrict__ Wk,
                                               const float* __restrict__ Wv,
                                               ushort_t* __restrict__ Wh,
                                               ushort_t* __restrict__ Wl) {
    int idx = (blockIdx.x * 256 + threadIdx.x) * 4;
#pragma unroll
    for (int e = 0; e < 4; e++) {
        int i = idx + e;
        int m = i >> 9, k = i & 511;
        float v = (m < C_Q) ? Wq[m * C_IN + k]
                 : (m < 2 * C_Q) ? Wk[(m - C_Q) * C_IN + k]
                 : Wv[(size_t)(m - 2 * C_Q) * C_IN + k];
        ushort_t h = f2h(v);
        Wh[i] = h;
        Wl[i] = f2h(v - h2f(h));
    }
}

// ---------------------------------------------------------------------------
// transpose + split: x [512][4096] fp32 -> xT hi/lo [4096][512] fp16
// Also zeroes D[4096] (rowsum accumulator) in the first 16 blocks of row y==0.
// ---------------------------------------------------------------------------
__global__ __launch_bounds__(256) void split_x(const float* __restrict__ x,
                                               ushort_t* __restrict__ xTh,
                                               ushort_t* __restrict__ xTl,
                                               float* __restrict__ D) {
    if (blockIdx.y == 0 && blockIdx.x < 16) D[blockIdx.x * 256 + threadIdx.x] = 0.f;

    __shared__ float tile[64][65];
    const int n0 = blockIdx.x * 64, k0 = blockIdx.y * 64;
    const int t = threadIdx.x;
#pragma unroll
    for (int it = 0; it < 4; it++) {
        int e = t + it * 256;
        int r = e >> 4, c4 = (e & 15) << 2;
        float4 v = *(const float4*)(x + (size_t)(k0 + r) * HW_N + n0 + c4);
        tile[r][c4 + 0] = v.x; tile[r][c4 + 1] = v.y;
        tile[r][c4 + 2] = v.z; tile[r][c4 + 3] = v.w;
    }
    __syncthreads();
    const int rr = t >> 2, kq = (t & 3) << 4;
    ushort_t h[16], l[16];
#pragma unroll
    for (int j = 0; j < 16; j++) {
        float v = tile[kq + j][rr];
        h[j] = f2h(v);
        l[j] = f2h(v - h2f(h[j]));
    }
    size_t o = (size_t)(n0 + rr) * C_IN + k0 + kq;
    *(uint4*)(xTh + o) = *(uint4*)h;
    *(uint4*)(xTh + o + 8) = *(uint4*)(h + 8);
    *(uint4*)(xTl + o) = *(uint4*)l;
    *(uint4*)(xTl + o + 8) = *(uint4*)(l + 8);
}

// ---------------------------------------------------------------------------
// 3-term fp16 hi/lo GEMM: C[m,n] = sum_k A[m,k]*B[n,k]
// 128x128 block tile, 4 waves, 16x16x32 f16 MFMA.
// EPI 0: Y epilogue (+bias, fp16 h/l; m<128 -> qkT transposed, else V)
// EPI 1: fp32 store (scores) + fused exp-rowsum atomicAdd into Dsum
// ---------------------------------------------------------------------------
template <int EPI>
__global__ __launch_bounds__(256) void mfma3(
    const ushort_t* __restrict__ Ah, const ushort_t* __restrict__ Al, int aStride,
    const ushort_t* __restrict__ Bh, const ushort_t* __restrict__ Bl, int bStride,
    int kLen,
    const float* __restrict__ bq, const float* __restrict__ bk,
    const float* __restrict__ bv,
    ushort_t* __restrict__ qkTh, ushort_t* __restrict__ qkTl,
    ushort_t* __restrict__ Vh, ushort_t* __restrict__ Vl,
    float* __restrict__ outF, float* __restrict__ Dsum) {
    __shared__ ushort_t sAh[128 * 32];
    __shared__ ushort_t sAl[128 * 32];
    __shared__ ushort_t sBh[128 * 32];
    __shared__ ushort_t sBl[128 * 32];

    const int tid = threadIdx.x, w = tid >> 6, lane = tid & 63;
    const int quad = lane >> 4, lr = lane & 15;
    const int m0 = blockIdx.y * 128, n0 = blockIdx.x * 128;

    const ushort_t* src;
    ushort_t* dst;
    int stride, rowBase;
    if (w == 0)      { src = Ah; dst = sAh; stride = aStride; rowBase = m0; }
    else if (w == 1) { src = Al; dst = sAl; stride = aStride; rowBase = m0; }
    else if (w == 2) { src = Bh; dst = sBh; stride = bStride; rowBase = n0; }
    else             { src = Bl; dst = sBl; stride = bStride; rowBase = n0; }
    const int cr = lane >> 2, kp = (lane & 3) << 3;
    const ushort_t* gk = src + (size_t)(rowBase + cr) * stride + kp;

    const int wm = (w & 1) * 64, wn = (w >> 1) * 64;

    float4v acc[4][4];
#pragma unroll
    for (int i = 0; i < 4; i++)
#pragma unroll
        for (int j = 0; j < 4; j++) acc[i][j] = (float4v){0.f, 0.f, 0.f, 0.f};

    for (int kk = 0; kk < kLen; kk += 32) {
#pragma unroll
        for (int c = 0; c < 8; c++)
            gl2lds16(gk + (size_t)(c * 16) * stride + kk, dst + c * 512);
        __syncthreads();

        short8 ah[4], al[4], bh[4], bl[4];
#pragma unroll
        for (int i = 0; i < 4; i++) {
            ah[i] = *(const short8*)&sAh[(wm + i * 16 + lr) * 32 + quad * 8];
            al[i] = *(const short8*)&sAl[(wm + i * 16 + lr) * 32 + quad * 8];
            bh[i] = *(const short8*)&sBh[(wn + i * 16 + lr) * 32 + quad * 8];
            bl[i] = *(const short8*)&sBl[(wn + i * 16 + lr) * 32 + quad * 8];
        }
#pragma unroll
        for (int i = 0; i < 4; i++)
#pragma unroll
            for (int j = 0; j < 4; j++) {
                acc[i][j] = __builtin_amdgcn_mfma_f32_16x16x32_f16(ah[i], bh[j], acc[i][j], 0, 0, 0);
                acc[i][j] = __builtin_amdgcn_mfma_f32_16x16x32_f16(ah[i], bl[j], acc[i][j], 0, 0, 0);
                acc[i][j] = __builtin_amdgcn_mfma_f32_16x16x32_f16(al[i], bh[j], acc[i][j], 0, 0, 0);
            }
        __syncthreads();
    }

    if (EPI == 0) {
#pragma unroll
        for (int i = 0; i < 4; i++)
#pragma unroll
            for (int j = 0; j < 4; j++)
#pragma unroll
                for (int r = 0; r < 4; r++) {
                    const int m = m0 + wm + i * 16 + quad * 4 + r;
                    const int n = n0 + wn + j * 16 + lr;
                    float bi = (m < C_Q) ? bq[m]
                              : (m < 2 * C_Q) ? bk[m - C_Q] : bv[m - 2 * C_Q];
                    float v = acc[i][j][r] + bi;
                    ushort_t h = f2h(v);
                    ushort_t lo = f2h(v - h2f(h));
                    if (m < 2 * C_Q) {
                        qkTh[(size_t)n * (2 * C_Q) + m] = h;
                        qkTl[(size_t)n * (2 * C_Q) + m] = lo;
                    } else {
                        Vh[(size_t)(m - 2 * C_Q) * HW_N + n] = h;
                        Vl[(size_t)(m - 2 * C_Q) * HW_N + n] = lo;
                    }
                }
    } else {
        // store S + fused per-row exp-sum partials
#pragma unroll
        for (int i = 0; i < 4; i++) {
#pragma unroll
            for (int r = 0; r < 4; r++) {
                float s = 0.f;
#pragma unroll
                for (int j = 0; j < 4; j++) {
                    const int m = m0 + wm + i * 16 + quad * 4 + r;
                    const int n = n0 + wn + j * 16 + lr;
                    outF[(size_t)m * HW_N + n] = acc[i][j][r];
                    s += __expf(acc[i][j][r]);
                }
                s += __shfl_xor(s, 1);
                s += __shfl_xor(s, 2);
                s += __shfl_xor(s, 4);
                s += __shfl_xor(s, 8);
                if (lr == 0)
                    atomicAdd(&Dsum[m0 + wm + i * 16 + quad * 4 + r], s);
            }
        }
    }
}

// ---------------------------------------------------------------------------
// feat GEMM v4: res[m,n] = sum_k (Vh+Vl)[m,k] * P[n,k],
//   P[n,k] = f16( exp2(S[n,k]*log2e - log2 D[n]) )
// Geometry: 256m x 256n block tile, 512 threads = 8 waves (4m x 2n),
// wave-tile 64x128 (acc[4][8], 256 B LDS reads per MFMA).  vs feat6:
//  - y-blocks drop 4->2, so the exp-convert work and per-CU S reads HALVE
//    (each S element converted 2x instead of 4x).
//  - Convert is moved AFTER the barrier and converts iteration it+1's S
//    (already in regs) into sP[nxt] while this iteration's MFMAs read
//    sP[cur]: the convert VALU overlaps other waves' MFMA on the SIMD, and
//    the S global->reg prefetch distance becomes 2 full iterations (~2500cy
//    of cover).  Hazards: sP[nxt] was last read before barrier(it-1);
//    vbuf[nxt] gl2lds drains at the end-of-iter barrier as before.
// LDS = 96 KB -> 1 block/CU, 8 waves = 2 waves/SIMD (same slots as feat6).
// grid (16, 2, 8) = 256 blocks; z=8 k-split partials unchanged.
// ---------------------------------------------------------------------------
__global__ __launch_bounds__(512, 2) void feat7(const ushort_t* __restrict__ Vh,
                                                const ushort_t* __restrict__ Vl,
                                                const float* __restrict__ S,
                                                const float* __restrict__ D,
                                                float* __restrict__ out,
                                                float* __restrict__ part,
                                                int kLen) {
    __shared__ ushort_t sVh[2][256 * 32];
    __shared__ ushort_t sVl[2][256 * 32];
    __shared__ ushort_t sP [2][256 * 32];

    const int tid = threadIdx.x, w = tid >> 6, lane = tid & 63;
    const int quad = lane >> 4, lr = lane & 15;
    const int m0 = blockIdx.y * 256, n0 = blockIdx.x * 256;
    const int k0 = blockIdx.z * kLen;

    // V staging: waves 0-3 -> Vh chunks (w&3)*4..+3, waves 4-7 -> Vl ditto.
    // chunk = 16 rows x 32 k x 2B = 1 KB = 64 lanes x 16B.  Global col is
    // pre-swizzled; linear gl2lds dest yields the swizzled LDS layout.
    const int crv = lane >> 2, uv = lane & 3;
    const int vcol = (uv ^ ((crv >> 1) & 3)) << 3;   // swizzled 16B unit
    const ushort_t* vbase = (w < 4) ? Vh : Vl;
    const ushort_t* gVsrc[4];
    int sOfs[4];
#pragma unroll
    for (int c = 0; c < 4; c++) {
        const int chunk = ((w & 3) * 4 + c);         // 0..15 within h or l
        gVsrc[c] = vbase + (size_t)(m0 + chunk * 16 + crv) * HW_N + vcol + k0;
        sOfs[c] = chunk * 512;
    }

    // S prefetch: thread owns rows pr+64c (c=0..3), 4-float k-unit pu.
    // sP write uses the same 16B-unit XOR swizzle as V ((row>>1)&3 ==
    // (pr>>1)&3 since 64c keeps bits 1-2) -> read side is one ds_read_b128.
    const int pr = tid >> 3, pu = tid & 7;
    const float* gS = S + (size_t)(n0 + pr) * HW_N + k0 + pu * 4;
    const int pdst = (((pu >> 1) ^ ((pr >> 1) & 3)) << 3) + ((pu & 1) << 2);
    float lrw[4];
#pragma unroll
    for (int c = 0; c < 4; c++) lrw[c] = -log2f(D[n0 + pr + 64 * c]);

    const int wm = (w & 3) * 64, wn = (w >> 2) * 128;

    float4 sreg[4];
    const int nIter = kLen >> 5;

    // prologue: load S(0), convert -> sP[0], prefetch S(1), stage V(0)
    {
#pragma unroll
        for (int c = 0; c < 4; c++)
            sreg[c] = *(const float4*)(gS + (size_t)(64 * c) * HW_N);
#pragma unroll
        for (int c = 0; c < 4; c++) gl2lds16(gVsrc[c], ((w < 4) ? sVh : sVl)[0] + sOfs[c]);
#pragma unroll
        for (int c = 0; c < 4; c++) {
            ushort_t h4[4];
            h4[0] = f2h(exp2f(fmaf(sreg[c].x, LOG2E, lrw[c])));
            h4[1] = f2h(exp2f(fmaf(sreg[c].y, LOG2E, lrw[c])));
            h4[2] = f2h(exp2f(fmaf(sreg[c].z, LOG2E, lrw[c])));
            h4[3] = f2h(exp2f(fmaf(sreg[c].w, LOG2E, lrw[c])));
            *(short4v*)&sP[0][(pr + 64 * c) * 32 + pdst] = *(short4v*)h4;
        }
        if (nIter > 1) {
#pragma unroll
            for (int c = 0; c < 4; c++)
                sreg[c] = *(const float4*)(gS + (size_t)(64 * c) * HW_N + 32);
        }
    }
    __syncthreads();  // V(0) + sP[0] visible

    float4v acc[4][8];
#pragma unroll
    for (int i = 0; i < 4; i++)
#pragma unroll
        for (int j = 0; j < 8; j++) acc[i][j] = (float4v){0.f, 0.f, 0.f, 0.f};

    for (int it = 0; it < nIter; ++it) {
        const int kk = it << 5;
        const int cur = it & 1, nxt = cur ^ 1;

        // issue next V tile first — flies through the whole MFMA section
        if (it + 1 < nIter) {
            ushort_t* db = ((w < 4) ? sVh : sVl)[nxt];
#pragma unroll
            for (int c = 0; c < 4; c++) gl2lds16(gVsrc[c] + kk + 32, db + sOfs[c]);
        }

        // convert S(it+1) (in regs) -> sP[nxt]; overlaps other waves' MFMA.
        if (it + 1 < nIter) {
#pragma unroll
            for (int c = 0; c < 4; c++) {
                ushort_t h4[4];
                h4[0] = f2h(exp2f(fmaf(sreg[c].x, LOG2E, lrw[c])));
                h4[1] = f2h(exp2f(fmaf(sreg[c].y, LOG2E, lrw[c])));
                h4[2] = f2h(exp2f(fmaf(sreg[c].z, LOG2E, lrw[c])));
                h4[3] = f2h(exp2f(fmaf(sreg[c].w, LOG2E, lrw[c])));
                *(short4v*)&sP[nxt][(pr + 64 * c) * 32 + pdst] = *(short4v*)h4;
            }
            if (it + 2 < nIter) {
#pragma unroll
                for (int c = 0; c < 4; c++)
                    sreg[c] = *(const float4*)(gS + (size_t)(64 * c) * HW_N + kk + 64);
            }
        }

        // B fragments: single b128 each (swizzle matches sP write)
        short8 bh[8];
#pragma unroll
        for (int j = 0; j < 8; j++) {
            const int row = wn + j * 16 + lr;
            bh[j] = *(const short8*)&sP[cur][row * 32 + ((quad ^ ((lr >> 1) & 3)) << 3)];
        }
#pragma unroll
        for (int i = 0; i < 4; i++) {
            const int row = wm + i * 16 + lr;
            const int up = (quad ^ ((lr >> 1) & 3)) << 3;
            short8 ah = *(const short8*)&sVh[cur][row * 32 + up];
            short8 al = *(const short8*)&sVl[cur][row * 32 + up];
#pragma unroll
            for (int j = 0; j < 8; j++)
                acc[i][j] = __builtin_amdgcn_mfma_f32_16x16x32_f16(ah, bh[j], acc[i][j], 0, 0, 0);
#pragma unroll
            for (int j = 0; j < 8; j++)
                acc[i][j] = __builtin_amdgcn_mfma_f32_16x16x32_f16(al, bh[j], acc[i][j], 0, 0, 0);
        }
        __syncthreads();  // drains: vbuf[nxt] gl2lds, sP[nxt] writes; orders WAR
    }

    float* o = (blockIdx.z == 0) ? out
             : (part + (size_t)(blockIdx.z - 1) * ((size_t)C_IN * HW_N));
#pragma unroll
    for (int i = 0; i < 4; i++)
#pragma unroll
        for (int j = 0; j < 8; j++)
#pragma unroll
            for (int r = 0; r < 4; r++) {
                const int m = m0 + wm + i * 16 + quad * 4 + r;
                const int n = n0 + wn + j * 16 + lr;
                o[(size_t)m * HW_N + n] = acc[i][j][r];
            }
}

// out = alpha * (out + sum of np partials), float4-vectorized
__global__ __launch_bounds__(256) void reduce_alphaN(float* __restrict__ out,
                                                     const float4* __restrict__ part,
                                                     size_t stride4,
                                                     const float* __restrict__ alpha,
                                                     int np) {
    const size_t i = (size_t)blockIdx.x * 256 + threadIdx.x;
    const float a = alpha[0];
    float4* out4 = (float4*)out;
    float4 s = out4[i];
    for (int p = 0; p < np; p++) {
        float4 t = part[i + (size_t)p * stride4];
        s.x += t.x; s.y += t.y; s.z += t.z; s.w += t.w;
    }
    float4 o;
    o.x = a * s.x; o.y = a * s.y; o.z = a * s.z; o.w = a * s.w;
    out4[i] = o;
}

// ---------------------------------------------------------------------------

extern "C" void kernel_launch(void* const* d_in, const int* in_sizes, int n_in,
                              void* d_out, int out_size, void* d_ws, size_t ws_size,
                              hipStream_t stream) {
    const float* x     = (const float*)d_in[0];
    const float* Wq    = (const float*)d_in[1];
    const float* bq    = (const float*)d_in[2];
    const float* Wk    = (const float*)d_in[3];
    const float* bk    = (const float*)d_in[4];
    const float* Wv    = (const float*)d_in[5];
    const float* bv    = (const float*)d_in[6];
    const float* alpha = (const float*)d_in[7];
    float* out = (float*)d_out;

    // ws layout (persistent region first — nothing here is overlaid):
    //   D         : 4096 fp32 rowsum               (16 KB)
    //   qkTh/qkTl : 4096 x 128 fp16 each           (2.0 MB)
    //   Vh/Vl     : 512 x 4096 fp16 each           (8.0 MB)
    //   Wh/Wl     : 640 x 512 fp16 each            (1.3 MB)
    //   scores    : 4096 x 4096 fp32               (67.1 MB)
    //     overlay (dead before scores written): xTh/xTl (8.4 MB)
    //   part      : (zsplit-1) x 512 x 4096 fp32   (58.7 MB at z=8)
    float* D = (float*)d_ws;
    ushort_t* qkTh = (ushort_t*)(D + HW_N);
    ushort_t* qkTl = qkTh + (size_t)HW_N * 2 * C_Q;
    ushort_t* Vh   = qkTl + (size_t)HW_N * 2 * C_Q;
    ushort_t* Vl   = Vh + (size_t)C_IN * HW_N;
    ushort_t* Wh   = Vl + (size_t)C_IN * HW_N;
    ushort_t* Wl   = Wh + (size_t)M_Y * C_IN;
    float* scores  = (float*)(Wl + (size_t)M_Y * C_IN);
    float* part    = scores + (size_t)HW_N * HW_N;

    ushort_t* xTh = (ushort_t*)scores;
    ushort_t* xTl = xTh + (size_t)HW_N * C_IN;

    // z-split: 8 needs 7 partial planes; fall back to 4 (correct, slower) if
    // the workspace can't hold them.
    const size_t planeF = (size_t)C_IN * HW_N;
    const size_t baseF  = (size_t)(part - (float*)d_ws);
    const int zsplit = (ws_size >= (baseF + 7 * planeF) * sizeof(float)) ? 8 : 4;

    split_w<<<dim3(M_Y * C_IN / 4 / 256), dim3(256), 0, stream>>>(Wq, Wk, Wv, Wh, Wl);

    for (int b = 0; b < NB; b++) {
        const float* xb = x + (size_t)b * C_IN * HW_N;
        float* outb = out + (size_t)b * C_IN * HW_N;

        split_x<<<dim3(HW_N / 64, C_IN / 64), dim3(256), 0, stream>>>(xb, xTh, xTl, D);

        // Y = W*x + b -> qkT (transposed, m<128) and V (m>=128), fp16 h/l
        mfma3<0><<<dim3(HW_N / 128, M_Y / 128), dim3(256), 0, stream>>>(
            Wh, Wl, C_IN, xTh, xTl, C_IN, C_IN,
            bq, bk, bv, qkTh, qkTl, Vh, Vl, nullptr, nullptr);

        // S[i,j] = sum_c q[c,i]k[c,j]  (fp32) + fused exp-rowsum into D
        mfma3<1><<<dim3(HW_N / 128, HW_N / 128), dim3(256), 0, stream>>>(
            qkTh, qkTl, 2 * C_Q, qkTh + C_Q, qkTl + C_Q, 2 * C_Q, C_Q,
            nullptr, nullptr, nullptr, nullptr, nullptr, nullptr, nullptr,
            scores, D);

        // res[c,i] = sum_j (Vh+Vl)[c,j] * f16(exp(S[i,j])/D[i]); z=0->out, z>0->part
        feat7<<<dim3(HW_N / 256, C_IN / 256, zsplit), dim3(512), 0, stream>>>(
            Vh, Vl, scores, D, outb, part, HW_N / zsplit);

        // out = alpha * (out + sum parts)
        reduce_alphaN<<<dim3((C_IN * HW_N / 4) / 256), dim3(256), 0, stream>>>(
            outb, (const float4*)part, (size_t)C_IN * HW_N / 4, alpha, zsplit - 1);
    }
}

// Round 4
// 580.472 us; speedup vs baseline: 1.1091x; 1.0350x over previous
//
#include <hip/hip_runtime.h>
#include <hip/hip_fp16.h>

// Problem constants (fixed by setup_inputs)
#define HW_N 4096   // 64*64 spatial positions
#define C_IN 512    // channels
#define C_Q  64     // query/key channels
#define NB   4      // batch
#define M_Y  640    // Cq + Cq + C stacked output rows
#define LOG2E 1.4426950408889634f

typedef __attribute__((ext_vector_type(8))) short short8;
typedef __attribute__((ext_vector_type(4))) short short4v;
typedef __attribute__((ext_vector_type(4))) float float4v;
typedef unsigned short ushort_t;

__device__ __forceinline__ ushort_t f2h(float x) {
    return __half_as_ushort(__float2half(x));  // RNE
}
__device__ __forceinline__ float h2f(ushort_t h) {
    return __half2float(__ushort_as_half(h));
}
__device__ __forceinline__ void gl2lds16(const ushort_t* g, ushort_t* l) {
    __builtin_amdgcn_global_load_lds(
        (const __attribute__((address_space(1))) unsigned int*)g,
        (__attribute__((address_space(3))) unsigned int*)l, 16, 0, 0);
}

// ---------------------------------------------------------------------------
// split stacked W = [Wq;Wk;Wv] (640x512 fp32) -> fp16 hi/lo (persistent region)
// ---------------------------------------------------------------------------
__global__ __launch_bounds__(256) void split_w(const float* __restrict__ Wq,
                                               const float* __restrict__ Wk,
                                               const float* __restrict__ Wv,
                                               ushort_t* __restrict__ Wh,
                                               ushort_t* __restrict__ Wl) {
    int idx = (blockIdx.x * 256 + threadIdx.x) * 4;
#pragma unroll
    for (int e = 0; e < 4; e++) {
        int i = idx + e;
        int m = i >> 9, k = i & 511;
        float v = (m < C_Q) ? Wq[m * C_IN + k]
                 : (m < 2 * C_Q) ? Wk[(m - C_Q) * C_IN + k]
                 : Wv[(size_t)(m - 2 * C_Q) * C_IN + k];
        ushort_t h = f2h(v);
        Wh[i] = h;
        Wl[i] = f2h(v - h2f(h));
    }
}

// ---------------------------------------------------------------------------
// transpose + split: x [512][4096] fp32 -> xT hi/lo [4096][512] fp16
// Also zeroes D[4096] (rowsum accumulator) in the first 16 blocks of row y==0.
// ---------------------------------------------------------------------------
__global__ __launch_bounds__(256) void split_x(const float* __restrict__ x,
                                               ushort_t* __restrict__ xTh,
                                               ushort_t* __restrict__ xTl,
                                               float* __restrict__ D) {
    if (blockIdx.y == 0 && blockIdx.x < 16) D[blockIdx.x * 256 + threadIdx.x] = 0.f;

    __shared__ float tile[64][65];
    const int n0 = blockIdx.x * 64, k0 = blockIdx.y * 64;
    const int t = threadIdx.x;
#pragma unroll
    for (int it = 0; it < 4; it++) {
        int e = t + it * 256;
        int r = e >> 4, c4 = (e & 15) << 2;
        float4 v = *(const float4*)(x + (size_t)(k0 + r) * HW_N + n0 + c4);
        tile[r][c4 + 0] = v.x; tile[r][c4 + 1] = v.y;
        tile[r][c4 + 2] = v.z; tile[r][c4 + 3] = v.w;
    }
    __syncthreads();
    const int rr = t >> 2, kq = (t & 3) << 4;
    ushort_t h[16], l[16];
#pragma unroll
    for (int j = 0; j < 16; j++) {
        float v = tile[kq + j][rr];
        h[j] = f2h(v);
        l[j] = f2h(v - h2f(h[j]));
    }
    size_t o = (size_t)(n0 + rr) * C_IN + k0 + kq;
    *(uint4*)(xTh + o) = *(uint4*)h;
    *(uint4*)(xTh + o + 8) = *(uint4*)(h + 8);
    *(uint4*)(xTl + o) = *(uint4*)l;
    *(uint4*)(xTl + o + 8) = *(uint4*)(l + 8);
}

// ---------------------------------------------------------------------------
// Y = W*x + b GEMM (replaces mfma3<0>): C[m,n] = sum_k A[m,k]*B[n,k], 3-term
// fp16 hi/lo.  128x128 tile, 4 waves, wave-tile 64x64 (acc[4][4]).
// Round-3 lesson: the old 2-barrier stage->compute loop exposed the full
// global->LDS latency on all 16 k-steps (MfmaUtil 5.7%, VALUBusy 6%, HBM 5%
// -- pure latency).  This version uses the PROVEN feat5/feat7 pipeline:
// double-buffered LDS, ONE barrier per k-step, next tile's global_load_lds
// issued before the MFMA section so it flies over ~48 MFMAs before the
// barrier's vmcnt(0) drain.  Fragment reads use the proven feat6 XOR swizzle
// (pre-swizzled global column, linear LDS dest) -> 0 bank conflicts.
// ---------------------------------------------------------------------------
__global__ __launch_bounds__(256, 1) void ygemm(
    const ushort_t* __restrict__ Ah, const ushort_t* __restrict__ Al,
    const ushort_t* __restrict__ Bh, const ushort_t* __restrict__ Bl,
    const float* __restrict__ bq, const float* __restrict__ bk,
    const float* __restrict__ bv,
    ushort_t* __restrict__ qkTh, ushort_t* __restrict__ qkTl,
    ushort_t* __restrict__ Vh, ushort_t* __restrict__ Vl) {
    __shared__ ushort_t sAh[2][128 * 32];
    __shared__ ushort_t sAl[2][128 * 32];
    __shared__ ushort_t sBh[2][128 * 32];
    __shared__ ushort_t sBl[2][128 * 32];

    const int tid = threadIdx.x, w = tid >> 6, lane = tid & 63;
    const int quad = lane >> 4, lr = lane & 15;
    const int m0 = blockIdx.y * 128, n0 = blockIdx.x * 128;

    // staging: wave w owns one of {Ah,Al,Bh,Bl}; 8 chunks of 16 rows.
    const ushort_t* src;
    ushort_t* dst0;
    int rowBase;
    if (w == 0)      { src = Ah; dst0 = sAh[0]; rowBase = m0; }
    else if (w == 1) { src = Al; dst0 = sAl[0]; rowBase = m0; }
    else if (w == 2) { src = Bh; dst0 = sBh[0]; rowBase = n0; }
    else             { src = Bl; dst0 = sBl[0]; rowBase = n0; }
    const int cr = lane >> 2, uv = lane & 3;
    const int kcol = (uv ^ ((cr >> 1) & 3)) << 3;   // pre-swizzled 16B k-unit
    const ushort_t* gk = src + (size_t)(rowBase + cr) * C_IN + kcol;

    const int wm = (w & 1) * 64, wn = (w >> 1) * 64;
    const int up = (quad ^ ((lr >> 1) & 3)) << 3;   // read-side swizzle

    float4v acc[4][4];
#pragma unroll
    for (int i = 0; i < 4; i++)
#pragma unroll
        for (int j = 0; j < 4; j++) acc[i][j] = (float4v){0.f, 0.f, 0.f, 0.f};

    // prologue: stage k-step 0 into buf 0
#pragma unroll
    for (int c = 0; c < 8; c++)
        gl2lds16(gk + (size_t)(c * 16) * C_IN, dst0 + c * 512);
    __syncthreads();

    const int NSTEP = C_IN / 32;    // 16
    for (int it = 0; it < NSTEP; ++it) {
        const int cur = it & 1, nxt = cur ^ 1;

        // issue next k-step's loads first — they fly over the MFMA section
        if (it + 1 < NSTEP) {
            ushort_t* db = dst0 + nxt * (128 * 32);
#pragma unroll
            for (int c = 0; c < 8; c++)
                gl2lds16(gk + (size_t)(c * 16) * C_IN + (it + 1) * 32, db + c * 512);
        }

        short8 ah[4], al[4], bh[4], bl[4];
#pragma unroll
        for (int i = 0; i < 4; i++) {
            ah[i] = *(const short8*)&sAh[cur][(wm + i * 16 + lr) * 32 + up];
            al[i] = *(const short8*)&sAl[cur][(wm + i * 16 + lr) * 32 + up];
            bh[i] = *(const short8*)&sBh[cur][(wn + i * 16 + lr) * 32 + up];
            bl[i] = *(const short8*)&sBl[cur][(wn + i * 16 + lr) * 32 + up];
        }
        // term-major order: 16 independent MFMAs between same-acc reuses
#pragma unroll
        for (int i = 0; i < 4; i++)
#pragma unroll
            for (int j = 0; j < 4; j++)
                acc[i][j] = __builtin_amdgcn_mfma_f32_16x16x32_f16(ah[i], bh[j], acc[i][j], 0, 0, 0);
#pragma unroll
        for (int i = 0; i < 4; i++)
#pragma unroll
            for (int j = 0; j < 4; j++)
                acc[i][j] = __builtin_amdgcn_mfma_f32_16x16x32_f16(ah[i], bl[j], acc[i][j], 0, 0, 0);
#pragma unroll
        for (int i = 0; i < 4; i++)
#pragma unroll
            for (int j = 0; j < 4; j++)
                acc[i][j] = __builtin_amdgcn_mfma_f32_16x16x32_f16(al[i], bh[j], acc[i][j], 0, 0, 0);
        __syncthreads();  // drains nxt's gl2lds (flew over MFMA); orders WAR
    }

    // epilogue: +bias, fp16 hi/lo split; m<128 -> qkT (transposed), else V
#pragma unroll
    for (int i = 0; i < 4; i++)
#pragma unroll
        for (int j = 0; j < 4; j++)
#pragma unroll
            for (int r = 0; r < 4; r++) {
                const int m = m0 + wm + i * 16 + quad * 4 + r;
                const int n = n0 + wn + j * 16 + lr;
                float bi = (m < C_Q) ? bq[m]
                          : (m < 2 * C_Q) ? bk[m - C_Q] : bv[m - 2 * C_Q];
                float v = acc[i][j][r] + bi;
                ushort_t h = f2h(v);
                ushort_t lo = f2h(v - h2f(h));
                if (m < 2 * C_Q) {
                    qkTh[(size_t)n * (2 * C_Q) + m] = h;
                    qkTl[(size_t)n * (2 * C_Q) + m] = lo;
                } else {
                    Vh[(size_t)(m - 2 * C_Q) * HW_N + n] = h;
                    Vl[(size_t)(m - 2 * C_Q) * HW_N + n] = lo;
                }
            }
}

// ---------------------------------------------------------------------------
// 3-term fp16 hi/lo GEMM (scores path): C[m,n] = sum_k A[m,k]*B[n,k]
// 128x128 block tile, 4 waves, 16x16x32 f16 MFMA.
// EPI 1: fp32 store (scores) + fused exp-rowsum atomicAdd into Dsum
// ---------------------------------------------------------------------------
template <int EPI>
__global__ __launch_bounds__(256) void mfma3(
    const ushort_t* __restrict__ Ah, const ushort_t* __restrict__ Al, int aStride,
    const ushort_t* __restrict__ Bh, const ushort_t* __restrict__ Bl, int bStride,
    int kLen,
    const float* __restrict__ bq, const float* __restrict__ bk,
    const float* __restrict__ bv,
    ushort_t* __restrict__ qkTh, ushort_t* __restrict__ qkTl,
    ushort_t* __restrict__ Vh, ushort_t* __restrict__ Vl,
    float* __restrict__ outF, float* __restrict__ Dsum) {
    __shared__ ushort_t sAh[128 * 32];
    __shared__ ushort_t sAl[128 * 32];
    __shared__ ushort_t sBh[128 * 32];
    __shared__ ushort_t sBl[128 * 32];

    const int tid = threadIdx.x, w = tid >> 6, lane = tid & 63;
    const int quad = lane >> 4, lr = lane & 15;
    const int m0 = blockIdx.y * 128, n0 = blockIdx.x * 128;

    const ushort_t* src;
    ushort_t* dst;
    int stride, rowBase;
    if (w == 0)      { src = Ah; dst = sAh; stride = aStride; rowBase = m0; }
    else if (w == 1) { src = Al; dst = sAl; stride = aStride; rowBase = m0; }
    else if (w == 2) { src = Bh; dst = sBh; stride = bStride; rowBase = n0; }
    else             { src = Bl; dst = sBl; stride = bStride; rowBase = n0; }
    const int cr = lane >> 2, kp = (lane & 3) << 3;
    const ushort_t* gk = src + (size_t)(rowBase + cr) * stride + kp;

    const int wm = (w & 1) * 64, wn = (w >> 1) * 64;

    float4v acc[4][4];
#pragma unroll
    for (int i = 0; i < 4; i++)
#pragma unroll
        for (int j = 0; j < 4; j++) acc[i][j] = (float4v){0.f, 0.f, 0.f, 0.f};

    for (int kk = 0; kk < kLen; kk += 32) {
#pragma unroll
        for (int c = 0; c < 8; c++)
            gl2lds16(gk + (size_t)(c * 16) * stride + kk, dst + c * 512);
        __syncthreads();

        short8 ah[4], al[4], bh[4], bl[4];
#pragma unroll
        for (int i = 0; i < 4; i++) {
            ah[i] = *(const short8*)&sAh[(wm + i * 16 + lr) * 32 + quad * 8];
            al[i] = *(const short8*)&sAl[(wm + i * 16 + lr) * 32 + quad * 8];
            bh[i] = *(const short8*)&sBh[(wn + i * 16 + lr) * 32 + quad * 8];
            bl[i] = *(const short8*)&sBl[(wn + i * 16 + lr) * 32 + quad * 8];
        }
#pragma unroll
        for (int i = 0; i < 4; i++)
#pragma unroll
            for (int j = 0; j < 4; j++) {
                acc[i][j] = __builtin_amdgcn_mfma_f32_16x16x32_f16(ah[i], bh[j], acc[i][j], 0, 0, 0);
                acc[i][j] = __builtin_amdgcn_mfma_f32_16x16x32_f16(ah[i], bl[j], acc[i][j], 0, 0, 0);
                acc[i][j] = __builtin_amdgcn_mfma_f32_16x16x32_f16(al[i], bh[j], acc[i][j], 0, 0, 0);
            }
        __syncthreads();
    }

    if (EPI == 0) {
        // (unused path — Y GEMM now handled by ygemm)
    } else {
        // store S + fused per-row exp-sum partials
#pragma unroll
        for (int i = 0; i < 4; i++) {
#pragma unroll
            for (int r = 0; r < 4; r++) {
                float s = 0.f;
#pragma unroll
                for (int j = 0; j < 4; j++) {
                    const int m = m0 + wm + i * 16 + quad * 4 + r;
                    const int n = n0 + wn + j * 16 + lr;
                    outF[(size_t)m * HW_N + n] = acc[i][j][r];
                    s += __expf(acc[i][j][r]);
                }
                s += __shfl_xor(s, 1);
                s += __shfl_xor(s, 2);
                s += __shfl_xor(s, 4);
                s += __shfl_xor(s, 8);
                if (lr == 0)
                    atomicAdd(&Dsum[m0 + wm + i * 16 + quad * 4 + r], s);
            }
        }
    }
}

// ---------------------------------------------------------------------------
// feat GEMM v4: res[m,n] = sum_k (Vh+Vl)[m,k] * P[n,k],
//   P[n,k] = f16( exp2(S[n,k]*log2e - log2 D[n]) )
// Geometry: 256m x 256n block tile, 512 threads = 8 waves (4m x 2n),
// wave-tile 64x128 (acc[4][8], 256 B LDS reads per MFMA).
// Convert runs AFTER the barrier on it+1's S (2-iter prefetch distance);
// convert VALU overlaps other waves' MFMA.  LDS 96 KB, 1 block/CU,
// grid (16,2,8) = 256 blocks; z=8 k-split partials.
// ---------------------------------------------------------------------------
__global__ __launch_bounds__(512, 2) void feat7(const ushort_t* __restrict__ Vh,
                                                const ushort_t* __restrict__ Vl,
                                                const float* __restrict__ S,
                                                const float* __restrict__ D,
                                                float* __restrict__ out,
                                                float* __restrict__ part,
                                                int kLen) {
    __shared__ ushort_t sVh[2][256 * 32];
    __shared__ ushort_t sVl[2][256 * 32];
    __shared__ ushort_t sP [2][256 * 32];

    const int tid = threadIdx.x, w = tid >> 6, lane = tid & 63;
    const int quad = lane >> 4, lr = lane & 15;
    const int m0 = blockIdx.y * 256, n0 = blockIdx.x * 256;
    const int k0 = blockIdx.z * kLen;

    // V staging: waves 0-3 -> Vh chunks (w&3)*4..+3, waves 4-7 -> Vl ditto.
    const int crv = lane >> 2, uv = lane & 3;
    const int vcol = (uv ^ ((crv >> 1) & 3)) << 3;   // swizzled 16B unit
    const ushort_t* vbase = (w < 4) ? Vh : Vl;
    const ushort_t* gVsrc[4];
    int sOfs[4];
#pragma unroll
    for (int c = 0; c < 4; c++) {
        const int chunk = ((w & 3) * 4 + c);         // 0..15 within h or l
        gVsrc[c] = vbase + (size_t)(m0 + chunk * 16 + crv) * HW_N + vcol + k0;
        sOfs[c] = chunk * 512;
    }

    // S prefetch: thread owns rows pr+64c (c=0..3), 4-float k-unit pu.
    const int pr = tid >> 3, pu = tid & 7;
    const float* gS = S + (size_t)(n0 + pr) * HW_N + k0 + pu * 4;
    const int pdst = (((pu >> 1) ^ ((pr >> 1) & 3)) << 3) + ((pu & 1) << 2);
    float lrw[4];
#pragma unroll
    for (int c = 0; c < 4; c++) lrw[c] = -log2f(D[n0 + pr + 64 * c]);

    const int wm = (w & 3) * 64, wn = (w >> 2) * 128;

    float4 sreg[4];
    const int nIter = kLen >> 5;

    // prologue: load S(0), convert -> sP[0], prefetch S(1), stage V(0)
    {
#pragma unroll
        for (int c = 0; c < 4; c++)
            sreg[c] = *(const float4*)(gS + (size_t)(64 * c) * HW_N);
#pragma unroll
        for (int c = 0; c < 4; c++) gl2lds16(gVsrc[c], ((w < 4) ? sVh : sVl)[0] + sOfs[c]);
#pragma unroll
        for (int c = 0; c < 4; c++) {
            ushort_t h4[4];
            h4[0] = f2h(exp2f(fmaf(sreg[c].x, LOG2E, lrw[c])));
            h4[1] = f2h(exp2f(fmaf(sreg[c].y, LOG2E, lrw[c])));
            h4[2] = f2h(exp2f(fmaf(sreg[c].z, LOG2E, lrw[c])));
            h4[3] = f2h(exp2f(fmaf(sreg[c].w, LOG2E, lrw[c])));
            *(short4v*)&sP[0][(pr + 64 * c) * 32 + pdst] = *(short4v*)h4;
        }
        if (nIter > 1) {
#pragma unroll
            for (int c = 0; c < 4; c++)
                sreg[c] = *(const float4*)(gS + (size_t)(64 * c) * HW_N + 32);
        }
    }
    __syncthreads();  // V(0) + sP[0] visible

    float4v acc[4][8];
#pragma unroll
    for (int i = 0; i < 4; i++)
#pragma unroll
        for (int j = 0; j < 8; j++) acc[i][j] = (float4v){0.f, 0.f, 0.f, 0.f};

    for (int it = 0; it < nIter; ++it) {
        const int kk = it << 5;
        const int cur = it & 1, nxt = cur ^ 1;

        // issue next V tile first — flies through the whole MFMA section
        if (it + 1 < nIter) {
            ushort_t* db = ((w < 4) ? sVh : sVl)[nxt];
#pragma unroll
            for (int c = 0; c < 4; c++) gl2lds16(gVsrc[c] + kk + 32, db + sOfs[c]);
        }

        // convert S(it+1) (in regs) -> sP[nxt]; overlaps other waves' MFMA.
        if (it + 1 < nIter) {
#pragma unroll
            for (int c = 0; c < 4; c++) {
                ushort_t h4[4];
                h4[0] = f2h(exp2f(fmaf(sreg[c].x, LOG2E, lrw[c])));
                h4[1] = f2h(exp2f(fmaf(sreg[c].y, LOG2E, lrw[c])));
                h4[2] = f2h(exp2f(fmaf(sreg[c].z, LOG2E, lrw[c])));
                h4[3] = f2h(exp2f(fmaf(sreg[c].w, LOG2E, lrw[c])));
                *(short4v*)&sP[nxt][(pr + 64 * c) * 32 + pdst] = *(short4v*)h4;
            }
            if (it + 2 < nIter) {
#pragma unroll
                for (int c = 0; c < 4; c++)
                    sreg[c] = *(const float4*)(gS + (size_t)(64 * c) * HW_N + kk + 64);
            }
        }

        // B fragments: single b128 each (swizzle matches sP write)
        short8 bh[8];
#pragma unroll
        for (int j = 0; j < 8; j++) {
            const int row = wn + j * 16 + lr;
            bh[j] = *(const short8*)&sP[cur][row * 32 + ((quad ^ ((lr >> 1) & 3)) << 3)];
        }
#pragma unroll
        for (int i = 0; i < 4; i++) {
            const int row = wm + i * 16 + lr;
            const int up = (quad ^ ((lr >> 1) & 3)) << 3;
            short8 ah = *(const short8*)&sVh[cur][row * 32 + up];
            short8 al = *(const short8*)&sVl[cur][row * 32 + up];
#pragma unroll
            for (int j = 0; j < 8; j++)
                acc[i][j] = __builtin_amdgcn_mfma_f32_16x16x32_f16(ah, bh[j], acc[i][j], 0, 0, 0);
#pragma unroll
            for (int j = 0; j < 8; j++)
                acc[i][j] = __builtin_amdgcn_mfma_f32_16x16x32_f16(al, bh[j], acc[i][j], 0, 0, 0);
        }
        __syncthreads();  // drains: vbuf[nxt] gl2lds, sP[nxt] writes; orders WAR
    }

    float* o = (blockIdx.z == 0) ? out
             : (part + (size_t)(blockIdx.z - 1) * ((size_t)C_IN * HW_N));
#pragma unroll
    for (int i = 0; i < 4; i++)
#pragma unroll
        for (int j = 0; j < 8; j++)
#pragma unroll
            for (int r = 0; r < 4; r++) {
                const int m = m0 + wm + i * 16 + quad * 4 + r;
                const int n = n0 + wn + j * 16 + lr;
                o[(size_t)m * HW_N + n] = acc[i][j][r];
            }
}

// out = alpha * (out + sum of np partials), float4-vectorized
__global__ __launch_bounds__(256) void reduce_alphaN(float* __restrict__ out,
                                                     const float4* __restrict__ part,
                                                     size_t stride4,
                                                     const float* __restrict__ alpha,
                                                     int np) {
    const size_t i = (size_t)blockIdx.x * 256 + threadIdx.x;
    const float a = alpha[0];
    float4* out4 = (float4*)out;
    float4 s = out4[i];
    for (int p = 0; p < np; p++) {
        float4 t = part[i + (size_t)p * stride4];
        s.x += t.x; s.y += t.y; s.z += t.z; s.w += t.w;
    }
    float4 o;
    o.x = a * s.x; o.y = a * s.y; o.z = a * s.z; o.w = a * s.w;
    out4[i] = o;
}

// ---------------------------------------------------------------------------

extern "C" void kernel_launch(void* const* d_in, const int* in_sizes, int n_in,
                              void* d_out, int out_size, void* d_ws, size_t ws_size,
                              hipStream_t stream) {
    const float* x     = (const float*)d_in[0];
    const float* Wq    = (const float*)d_in[1];
    const float* bq    = (const float*)d_in[2];
    const float* Wk    = (const float*)d_in[3];
    const float* bk    = (const float*)d_in[4];
    const float* Wv    = (const float*)d_in[5];
    const float* bv    = (const float*)d_in[6];
    const float* alpha = (const float*)d_in[7];
    float* out = (float*)d_out;

    // ws layout (persistent region first — nothing here is overlaid):
    //   D         : 4096 fp32 rowsum               (16 KB)
    //   qkTh/qkTl : 4096 x 128 fp16 each           (2.0 MB)
    //   Vh/Vl     : 512 x 4096 fp16 each           (8.0 MB)
    //   Wh/Wl     : 640 x 512 fp16 each            (1.3 MB)
    //   scores    : 4096 x 4096 fp32               (67.1 MB)
    //     overlay (dead before scores written): xTh/xTl (8.4 MB)
    //   part      : (zsplit-1) x 512 x 4096 fp32   (58.7 MB at z=8)
    float* D = (float*)d_ws;
    ushort_t* qkTh = (ushort_t*)(D + HW_N);
    ushort_t* qkTl = qkTh + (size_t)HW_N * 2 * C_Q;
    ushort_t* Vh   = qkTl + (size_t)HW_N * 2 * C_Q;
    ushort_t* Vl   = Vh + (size_t)C_IN * HW_N;
    ushort_t* Wh   = Vl + (size_t)C_IN * HW_N;
    ushort_t* Wl   = Wh + (size_t)M_Y * C_IN;
    float* scores  = (float*)(Wl + (size_t)M_Y * C_IN);
    float* part    = scores + (size_t)HW_N * HW_N;

    ushort_t* xTh = (ushort_t*)scores;
    ushort_t* xTl = xTh + (size_t)HW_N * C_IN;

    // z-split: 8 needs 7 partial planes; fall back to 4 (correct, slower) if
    // the workspace can't hold them.
    const size_t planeF = (size_t)C_IN * HW_N;
    const size_t baseF  = (size_t)(part - (float*)d_ws);
    const int zsplit = (ws_size >= (baseF + 7 * planeF) * sizeof(float)) ? 8 : 4;

    split_w<<<dim3(M_Y * C_IN / 4 / 256), dim3(256), 0, stream>>>(Wq, Wk, Wv, Wh, Wl);

    for (int b = 0; b < NB; b++) {
        const float* xb = x + (size_t)b * C_IN * HW_N;
        float* outb = out + (size_t)b * C_IN * HW_N;

        split_x<<<dim3(HW_N / 64, C_IN / 64), dim3(256), 0, stream>>>(xb, xTh, xTl, D);

        // Y = W*x + b -> qkT (transposed, m<128) and V (m>=128), fp16 h/l
        ygemm<<<dim3(HW_N / 128, M_Y / 128), dim3(256), 0, stream>>>(
            Wh, Wl, xTh, xTl, bq, bk, bv, qkTh, qkTl, Vh, Vl);

        // S[i,j] = sum_c q[c,i]k[c,j]  (fp32) + fused exp-rowsum into D
        mfma3<1><<<dim3(HW_N / 128, HW_N / 128), dim3(256), 0, stream>>>(
            qkTh, qkTl, 2 * C_Q, qkTh + C_Q, qkTl + C_Q, 2 * C_Q, C_Q,
            nullptr, nullptr, nullptr, nullptr, nullptr, nullptr, nullptr,
            scores, D);

        // res[c,i] = sum_j (Vh+Vl)[c,j] * f16(exp(S[i,j])/D[i]); z=0->out, z>0->part
        feat7<<<dim3(HW_N / 256, C_IN / 256, zsplit), dim3(512), 0, stream>>>(
            Vh, Vl, scores, D, outb, part, HW_N / zsplit);

        // out = alpha * (out + sum parts)
        reduce_alphaN<<<dim3((C_IN * HW_N / 4) / 256), dim3(256), 0, stream>>>(
            outb, (const float4*)part, (size_t)C_IN * HW_N / 4, alpha, zsplit - 1);
    }
}

// Round 5
// 575.493 us; speedup vs baseline: 1.1187x; 1.0087x over previous
//
#include <hip/hip_runtime.h>
#include <hip/hip_fp16.h>

// Problem constants (fixed by setup_inputs)
#define HW_N 4096   // 64*64 spatial positions
#define C_IN 512    // channels
#define C_Q  64     // query/key channels
#define NB   4      // batch
#define M_Y  640    // Cq + Cq + C stacked output rows
#define LOG2E 1.4426950408889634f

typedef __attribute__((ext_vector_type(8))) short short8;
typedef __attribute__((ext_vector_type(4))) short short4v;
typedef __attribute__((ext_vector_type(4))) float float4v;
typedef unsigned short ushort_t;

__device__ __forceinline__ ushort_t f2h(float x) {
    return __half_as_ushort(__float2half(x));  // RNE
}
__device__ __forceinline__ float h2f(ushort_t h) {
    return __half2float(__ushort_as_half(h));
}
__device__ __forceinline__ void gl2lds16(const ushort_t* g, ushort_t* l) {
    __builtin_amdgcn_global_load_lds(
        (const __attribute__((address_space(1))) unsigned int*)g,
        (__attribute__((address_space(3))) unsigned int*)l, 16, 0, 0);
}

// ---------------------------------------------------------------------------
// split stacked W = [Wq;Wk;Wv] (640x512 fp32) -> fp16 hi/lo (persistent region)
// ---------------------------------------------------------------------------
__global__ __launch_bounds__(256) void split_w(const float* __restrict__ Wq,
                                               const float* __restrict__ Wk,
                                               const float* __restrict__ Wv,
                                               ushort_t* __restrict__ Wh,
                                               ushort_t* __restrict__ Wl) {
    int idx = (blockIdx.x * 256 + threadIdx.x) * 4;
#pragma unroll
    for (int e = 0; e < 4; e++) {
        int i = idx + e;
        int m = i >> 9, k = i & 511;
        float v = (m < C_Q) ? Wq[m * C_IN + k]
                 : (m < 2 * C_Q) ? Wk[(m - C_Q) * C_IN + k]
                 : Wv[(size_t)(m - 2 * C_Q) * C_IN + k];
        ushort_t h = f2h(v);
        Wh[i] = h;
        Wl[i] = f2h(v - h2f(h));
    }
}

// ---------------------------------------------------------------------------
// transpose + split: x [512][4096] fp32 -> xT hi/lo [4096][512] fp16
// Also zeroes D[4096] (rowsum accumulator) in the first 16 blocks of row y==0.
// ---------------------------------------------------------------------------
__global__ __launch_bounds__(256) void split_x(const float* __restrict__ x,
                                               ushort_t* __restrict__ xTh,
                                               ushort_t* __restrict__ xTl,
                                               float* __restrict__ D) {
    if (blockIdx.y == 0 && blockIdx.x < 16) D[blockIdx.x * 256 + threadIdx.x] = 0.f;

    __shared__ float tile[64][65];
    const int n0 = blockIdx.x * 64, k0 = blockIdx.y * 64;
    const int t = threadIdx.x;
#pragma unroll
    for (int it = 0; it < 4; it++) {
        int e = t + it * 256;
        int r = e >> 4, c4 = (e & 15) << 2;
        float4 v = *(const float4*)(x + (size_t)(k0 + r) * HW_N + n0 + c4);
        tile[r][c4 + 0] = v.x; tile[r][c4 + 1] = v.y;
        tile[r][c4 + 2] = v.z; tile[r][c4 + 3] = v.w;
    }
    __syncthreads();
    const int rr = t >> 2, kq = (t & 3) << 4;
    ushort_t h[16], l[16];
#pragma unroll
    for (int j = 0; j < 16; j++) {
        float v = tile[kq + j][rr];
        h[j] = f2h(v);
        l[j] = f2h(v - h2f(h[j]));
    }
    size_t o = (size_t)(n0 + rr) * C_IN + k0 + kq;
    *(uint4*)(xTh + o) = *(uint4*)h;
    *(uint4*)(xTh + o + 8) = *(uint4*)(h + 8);
    *(uint4*)(xTl + o) = *(uint4*)l;
    *(uint4*)(xTl + o + 8) = *(uint4*)(l + 8);
}

// ---------------------------------------------------------------------------
// Y = W*x + b GEMM: C[m,n] = sum_k A[m,k]*B[n,k], 3-term fp16 hi/lo.
// 128x128 tile, 4 waves, wave-tile 64x64.  Pipelined: double-buffered LDS,
// ONE barrier per k-step, next tile's gl2lds flies over the MFMA section.
// Pre-swizzled global column + swizzled b128 reads -> 0 bank conflicts.
// ---------------------------------------------------------------------------
__global__ __launch_bounds__(256, 1) void ygemm(
    const ushort_t* __restrict__ Ah, const ushort_t* __restrict__ Al,
    const ushort_t* __restrict__ Bh, const ushort_t* __restrict__ Bl,
    const float* __restrict__ bq, const float* __restrict__ bk,
    const float* __restrict__ bv,
    ushort_t* __restrict__ qkTh, ushort_t* __restrict__ qkTl,
    ushort_t* __restrict__ Vh, ushort_t* __restrict__ Vl) {
    __shared__ ushort_t sAh[2][128 * 32];
    __shared__ ushort_t sAl[2][128 * 32];
    __shared__ ushort_t sBh[2][128 * 32];
    __shared__ ushort_t sBl[2][128 * 32];

    const int tid = threadIdx.x, w = tid >> 6, lane = tid & 63;
    const int quad = lane >> 4, lr = lane & 15;
    const int m0 = blockIdx.y * 128, n0 = blockIdx.x * 128;

    // staging: wave w owns one of {Ah,Al,Bh,Bl}; 8 chunks of 16 rows.
    const ushort_t* src;
    ushort_t* dst0;
    int rowBase;
    if (w == 0)      { src = Ah; dst0 = sAh[0]; rowBase = m0; }
    else if (w == 1) { src = Al; dst0 = sAl[0]; rowBase = m0; }
    else if (w == 2) { src = Bh; dst0 = sBh[0]; rowBase = n0; }
    else             { src = Bl; dst0 = sBl[0]; rowBase = n0; }
    const int cr = lane >> 2, uv = lane & 3;
    const int kcol = (uv ^ ((cr >> 1) & 3)) << 3;   // pre-swizzled 16B k-unit
    const ushort_t* gk = src + (size_t)(rowBase + cr) * C_IN + kcol;

    const int wm = (w & 1) * 64, wn = (w >> 1) * 64;
    const int up = (quad ^ ((lr >> 1) & 3)) << 3;   // read-side swizzle

    float4v acc[4][4];
#pragma unroll
    for (int i = 0; i < 4; i++)
#pragma unroll
        for (int j = 0; j < 4; j++) acc[i][j] = (float4v){0.f, 0.f, 0.f, 0.f};

    // prologue: stage k-step 0 into buf 0
#pragma unroll
    for (int c = 0; c < 8; c++)
        gl2lds16(gk + (size_t)(c * 16) * C_IN, dst0 + c * 512);
    __syncthreads();

    const int NSTEP = C_IN / 32;    // 16
    for (int it = 0; it < NSTEP; ++it) {
        const int cur = it & 1, nxt = cur ^ 1;

        // issue next k-step's loads first — they fly over the MFMA section
        if (it + 1 < NSTEP) {
            ushort_t* db = dst0 + nxt * (128 * 32);
#pragma unroll
            for (int c = 0; c < 8; c++)
                gl2lds16(gk + (size_t)(c * 16) * C_IN + (it + 1) * 32, db + c * 512);
        }

        short8 ah[4], al[4], bh[4], bl[4];
#pragma unroll
        for (int i = 0; i < 4; i++) {
            ah[i] = *(const short8*)&sAh[cur][(wm + i * 16 + lr) * 32 + up];
            al[i] = *(const short8*)&sAl[cur][(wm + i * 16 + lr) * 32 + up];
            bh[i] = *(const short8*)&sBh[cur][(wn + i * 16 + lr) * 32 + up];
            bl[i] = *(const short8*)&sBl[cur][(wn + i * 16 + lr) * 32 + up];
        }
        // term-major order: 16 independent MFMAs between same-acc reuses
#pragma unroll
        for (int i = 0; i < 4; i++)
#pragma unroll
            for (int j = 0; j < 4; j++)
                acc[i][j] = __builtin_amdgcn_mfma_f32_16x16x32_f16(ah[i], bh[j], acc[i][j], 0, 0, 0);
#pragma unroll
        for (int i = 0; i < 4; i++)
#pragma unroll
            for (int j = 0; j < 4; j++)
                acc[i][j] = __builtin_amdgcn_mfma_f32_16x16x32_f16(ah[i], bl[j], acc[i][j], 0, 0, 0);
#pragma unroll
        for (int i = 0; i < 4; i++)
#pragma unroll
            for (int j = 0; j < 4; j++)
                acc[i][j] = __builtin_amdgcn_mfma_f32_16x16x32_f16(al[i], bh[j], acc[i][j], 0, 0, 0);
        __syncthreads();  // drains nxt's gl2lds (flew over MFMA); orders WAR
    }

    // epilogue: +bias, fp16 hi/lo split; m<128 -> qkT (transposed), else V
#pragma unroll
    for (int i = 0; i < 4; i++)
#pragma unroll
        for (int j = 0; j < 4; j++)
#pragma unroll
            for (int r = 0; r < 4; r++) {
                const int m = m0 + wm + i * 16 + quad * 4 + r;
                const int n = n0 + wn + j * 16 + lr;
                float bi = (m < C_Q) ? bq[m]
                          : (m < 2 * C_Q) ? bk[m - C_Q] : bv[m - 2 * C_Q];
                float v = acc[i][j][r] + bi;
                ushort_t h = f2h(v);
                ushort_t lo = f2h(v - h2f(h));
                if (m < 2 * C_Q) {
                    qkTh[(size_t)n * (2 * C_Q) + m] = h;
                    qkTl[(size_t)n * (2 * C_Q) + m] = lo;
                } else {
                    Vh[(size_t)(m - 2 * C_Q) * HW_N + n] = h;
                    Vl[(size_t)(m - 2 * C_Q) * HW_N + n] = lo;
                }
            }
}

// ---------------------------------------------------------------------------
// S = q^T k GEMM (replaces mfma3<1>): S[m,n] = sum_k q[k,m]*k[k,n], 3-term
// fp16 hi/lo, kLen = 64 (2 k-steps).  Round-4 theory: the old version kept
// the round-3-condemned 2-barrier stage->drain->compute loop and un-swizzled
// fragment reads (655K bank-conflict cycles) and was ~2.5x off its ~15 us
// floor.  This is the proven ygemm pipeline: double-buffered 64 KB LDS
// (-> 2 blocks/CU, 8 waves/CU), pre-swizzled gl2lds staging, swizzled
// single-b128 fragment reads, term-major MFMA, one barrier per k-step.
// Epilogue: fp32 S store + fused per-row exp-sum atomicAdd into Dsum.
// A = qkT[:, 0:64] (q), B = qkT[:, 64:128] (k); both stride 2*C_Q = 128.
// ---------------------------------------------------------------------------
__global__ __launch_bounds__(256) void qkgemm(const ushort_t* __restrict__ qkTh_,
                                              const ushort_t* __restrict__ qkTl_,
                                              float* __restrict__ outF,
                                              float* __restrict__ Dsum) {
    __shared__ ushort_t sAh[2][128 * 32];
    __shared__ ushort_t sAl[2][128 * 32];
    __shared__ ushort_t sBh[2][128 * 32];
    __shared__ ushort_t sBl[2][128 * 32];

    const int tid = threadIdx.x, w = tid >> 6, lane = tid & 63;
    const int quad = lane >> 4, lr = lane & 15;
    const int m0 = blockIdx.y * 128, n0 = blockIdx.x * 128;

    // staging: wave 0->q-hi, 1->q-lo, 2->k-hi, 3->k-lo; 8 chunks of 16 rows.
    const ushort_t* src = ((w & 1) ? qkTl_ : qkTh_) + ((w >> 1) ? C_Q : 0);
    ushort_t* dst0 = (w == 0) ? sAh[0] : (w == 1) ? sAl[0]
                   : (w == 2) ? sBh[0] : sBl[0];
    const int rowBase = (w >> 1) ? n0 : m0;
    const int cr = lane >> 2, uv = lane & 3;
    const int kcol = (uv ^ ((cr >> 1) & 3)) << 3;   // pre-swizzled 16B k-unit
    const ushort_t* gk = src + (size_t)(rowBase + cr) * (2 * C_Q) + kcol;

    const int wm = (w & 1) * 64, wn = (w >> 1) * 64;
    const int up = (quad ^ ((lr >> 1) & 3)) << 3;   // read-side swizzle

    float4v acc[4][4];
#pragma unroll
    for (int i = 0; i < 4; i++)
#pragma unroll
        for (int j = 0; j < 4; j++) acc[i][j] = (float4v){0.f, 0.f, 0.f, 0.f};

    // prologue: stage k-step 0 into buf 0
#pragma unroll
    for (int c = 0; c < 8; c++)
        gl2lds16(gk + (size_t)(c * 16) * (2 * C_Q), dst0 + c * 512);
    __syncthreads();

    const int NSTEP = C_Q / 32;     // 2
#pragma unroll
    for (int it = 0; it < NSTEP; ++it) {
        const int cur = it & 1, nxt = cur ^ 1;

        if (it + 1 < NSTEP) {
            ushort_t* db = dst0 + nxt * (128 * 32);
#pragma unroll
            for (int c = 0; c < 8; c++)
                gl2lds16(gk + (size_t)(c * 16) * (2 * C_Q) + (it + 1) * 32, db + c * 512);
        }

        short8 ah[4], al[4], bh[4], bl[4];
#pragma unroll
        for (int i = 0; i < 4; i++) {
            ah[i] = *(const short8*)&sAh[cur][(wm + i * 16 + lr) * 32 + up];
            al[i] = *(const short8*)&sAl[cur][(wm + i * 16 + lr) * 32 + up];
            bh[i] = *(const short8*)&sBh[cur][(wn + i * 16 + lr) * 32 + up];
            bl[i] = *(const short8*)&sBl[cur][(wn + i * 16 + lr) * 32 + up];
        }
#pragma unroll
        for (int i = 0; i < 4; i++)
#pragma unroll
            for (int j = 0; j < 4; j++)
                acc[i][j] = __builtin_amdgcn_mfma_f32_16x16x32_f16(ah[i], bh[j], acc[i][j], 0, 0, 0);
#pragma unroll
        for (int i = 0; i < 4; i++)
#pragma unroll
            for (int j = 0; j < 4; j++)
                acc[i][j] = __builtin_amdgcn_mfma_f32_16x16x32_f16(ah[i], bl[j], acc[i][j], 0, 0, 0);
#pragma unroll
        for (int i = 0; i < 4; i++)
#pragma unroll
            for (int j = 0; j < 4; j++)
                acc[i][j] = __builtin_amdgcn_mfma_f32_16x16x32_f16(al[i], bh[j], acc[i][j], 0, 0, 0);
        if (it + 1 < NSTEP) __syncthreads();  // drains nxt's gl2lds
    }

    // epilogue: store S + fused per-row exp-sum partials
#pragma unroll
    for (int i = 0; i < 4; i++) {
#pragma unroll
        for (int r = 0; r < 4; r++) {
            float s = 0.f;
#pragma unroll
            for (int j = 0; j < 4; j++) {
                const int m = m0 + wm + i * 16 + quad * 4 + r;
                const int n = n0 + wn + j * 16 + lr;
                outF[(size_t)m * HW_N + n] = acc[i][j][r];
                s += __expf(acc[i][j][r]);
            }
            s += __shfl_xor(s, 1);
            s += __shfl_xor(s, 2);
            s += __shfl_xor(s, 4);
            s += __shfl_xor(s, 8);
            if (lr == 0)
                atomicAdd(&Dsum[m0 + wm + i * 16 + quad * 4 + r], s);
        }
    }
}

// ---------------------------------------------------------------------------
// feat GEMM v4.1: res[m,n] = sum_k (Vh+Vl)[m,k] * P[n,k],
//   P[n,k] = f16( exp2(S[n,k]*log2e - log2 D[n]) )
// 256m x 256n tile, 512 threads = 8 waves (4m x 2n), wave-tile 64x128.
// Convert runs AFTER the barrier on it+1's S (2-iter prefetch distance).
// v4.1: B-fragment reads moved BEFORE the convert — compiler can't reorder
// ds_read sP[cur] past ds_write sP[nxt] (runtime indices), so without this
// the fragment-read latency sat between convert and MFMA instead of hiding
// under the convert VALU.  LDS 96 KB, 1 block/CU, grid (16,2,8); z=8 k-split.
// ---------------------------------------------------------------------------
__global__ __launch_bounds__(512, 2) void feat7(const ushort_t* __restrict__ Vh,
                                                const ushort_t* __restrict__ Vl,
                                                const float* __restrict__ S,
                                                const float* __restrict__ D,
                                                float* __restrict__ out,
                                                float* __restrict__ part,
                                                int kLen) {
    __shared__ ushort_t sVh[2][256 * 32];
    __shared__ ushort_t sVl[2][256 * 32];
    __shared__ ushort_t sP [2][256 * 32];

    const int tid = threadIdx.x, w = tid >> 6, lane = tid & 63;
    const int quad = lane >> 4, lr = lane & 15;
    const int m0 = blockIdx.y * 256, n0 = blockIdx.x * 256;
    const int k0 = blockIdx.z * kLen;

    // V staging: waves 0-3 -> Vh chunks (w&3)*4..+3, waves 4-7 -> Vl ditto.
    const int crv = lane >> 2, uv = lane & 3;
    const int vcol = (uv ^ ((crv >> 1) & 3)) << 3;   // swizzled 16B unit
    const ushort_t* vbase = (w < 4) ? Vh : Vl;
    const ushort_t* gVsrc[4];
    int sOfs[4];
#pragma unroll
    for (int c = 0; c < 4; c++) {
        const int chunk = ((w & 3) * 4 + c);         // 0..15 within h or l
        gVsrc[c] = vbase + (size_t)(m0 + chunk * 16 + crv) * HW_N + vcol + k0;
        sOfs[c] = chunk * 512;
    }

    // S prefetch: thread owns rows pr+64c (c=0..3), 4-float k-unit pu.
    const int pr = tid >> 3, pu = tid & 7;
    const float* gS = S + (size_t)(n0 + pr) * HW_N + k0 + pu * 4;
    const int pdst = (((pu >> 1) ^ ((pr >> 1) & 3)) << 3) + ((pu & 1) << 2);
    float lrw[4];
#pragma unroll
    for (int c = 0; c < 4; c++) lrw[c] = -log2f(D[n0 + pr + 64 * c]);

    const int wm = (w & 3) * 64, wn = (w >> 2) * 128;

    float4 sreg[4];
    const int nIter = kLen >> 5;

    // prologue: load S(0), convert -> sP[0], prefetch S(1), stage V(0)
    {
#pragma unroll
        for (int c = 0; c < 4; c++)
            sreg[c] = *(const float4*)(gS + (size_t)(64 * c) * HW_N);
#pragma unroll
        for (int c = 0; c < 4; c++) gl2lds16(gVsrc[c], ((w < 4) ? sVh : sVl)[0] + sOfs[c]);
#pragma unroll
        for (int c = 0; c < 4; c++) {
            ushort_t h4[4];
            h4[0] = f2h(exp2f(fmaf(sreg[c].x, LOG2E, lrw[c])));
            h4[1] = f2h(exp2f(fmaf(sreg[c].y, LOG2E, lrw[c])));
            h4[2] = f2h(exp2f(fmaf(sreg[c].z, LOG2E, lrw[c])));
            h4[3] = f2h(exp2f(fmaf(sreg[c].w, LOG2E, lrw[c])));
            *(short4v*)&sP[0][(pr + 64 * c) * 32 + pdst] = *(short4v*)h4;
        }
        if (nIter > 1) {
#pragma unroll
            for (int c = 0; c < 4; c++)
                sreg[c] = *(const float4*)(gS + (size_t)(64 * c) * HW_N + 32);
        }
    }
    __syncthreads();  // V(0) + sP[0] visible

    float4v acc[4][8];
#pragma unroll
    for (int i = 0; i < 4; i++)
#pragma unroll
        for (int j = 0; j < 8; j++) acc[i][j] = (float4v){0.f, 0.f, 0.f, 0.f};

    for (int it = 0; it < nIter; ++it) {
        const int kk = it << 5;
        const int cur = it & 1, nxt = cur ^ 1;

        // issue next V tile first — flies through the whole MFMA section
        if (it + 1 < nIter) {
            ushort_t* db = ((w < 4) ? sVh : sVl)[nxt];
#pragma unroll
            for (int c = 0; c < 4; c++) gl2lds16(gVsrc[c] + kk + 32, db + sOfs[c]);
        }

        // B fragments FIRST: their ds_read latency hides under the convert
        short8 bh[8];
#pragma unroll
        for (int j = 0; j < 8; j++) {
            const int row = wn + j * 16 + lr;
            bh[j] = *(const short8*)&sP[cur][row * 32 + ((quad ^ ((lr >> 1) & 3)) << 3)];
        }

        // convert S(it+1) (in regs) -> sP[nxt]; overlaps other waves' MFMA.
        if (it + 1 < nIter) {
#pragma unroll
            for (int c = 0; c < 4; c++) {
                ushort_t h4[4];
                h4[0] = f2h(exp2f(fmaf(sreg[c].x, LOG2E, lrw[c])));
                h4[1] = f2h(exp2f(fmaf(sreg[c].y, LOG2E, lrw[c])));
                h4[2] = f2h(exp2f(fmaf(sreg[c].z, LOG2E, lrw[c])));
                h4[3] = f2h(exp2f(fmaf(sreg[c].w, LOG2E, lrw[c])));
                *(short4v*)&sP[nxt][(pr + 64 * c) * 32 + pdst] = *(short4v*)h4;
            }
            if (it + 2 < nIter) {
#pragma unroll
                for (int c = 0; c < 4; c++)
                    sreg[c] = *(const float4*)(gS + (size_t)(64 * c) * HW_N + kk + 64);
            }
        }

#pragma unroll
        for (int i = 0; i < 4; i++) {
            const int row = wm + i * 16 + lr;
            const int up = (quad ^ ((lr >> 1) & 3)) << 3;
            short8 ah = *(const short8*)&sVh[cur][row * 32 + up];
            short8 al = *(const short8*)&sVl[cur][row * 32 + up];
#pragma unroll
            for (int j = 0; j < 8; j++)
                acc[i][j] = __builtin_amdgcn_mfma_f32_16x16x32_f16(ah, bh[j], acc[i][j], 0, 0, 0);
#pragma unroll
            for (int j = 0; j < 8; j++)
                acc[i][j] = __builtin_amdgcn_mfma_f32_16x16x32_f16(al, bh[j], acc[i][j], 0, 0, 0);
        }
        __syncthreads();  // drains: vbuf[nxt] gl2lds, sP[nxt] writes; orders WAR
    }

    float* o = (blockIdx.z == 0) ? out
             : (part + (size_t)(blockIdx.z - 1) * ((size_t)C_IN * HW_N));
#pragma unroll
    for (int i = 0; i < 4; i++)
#pragma unroll
        for (int j = 0; j < 8; j++)
#pragma unroll
            for (int r = 0; r < 4; r++) {
                const int m = m0 + wm + i * 16 + quad * 4 + r;
                const int n = n0 + wn + j * 16 + lr;
                o[(size_t)m * HW_N + n] = acc[i][j][r];
            }
}

// out = alpha * (out + sum of np partials), float4-vectorized
__global__ __launch_bounds__(256) void reduce_alphaN(float* __restrict__ out,
                                                     const float4* __restrict__ part,
                                                     size_t stride4,
                                                     const float* __restrict__ alpha,
                                                     int np) {
    const size_t i = (size_t)blockIdx.x * 256 + threadIdx.x;
    const float a = alpha[0];
    float4* out4 = (float4*)out;
    float4 s = out4[i];
    for (int p = 0; p < np; p++) {
        float4 t = part[i + (size_t)p * stride4];
        s.x += t.x; s.y += t.y; s.z += t.z; s.w += t.w;
    }
    float4 o;
    o.x = a * s.x; o.y = a * s.y; o.z = a * s.z; o.w = a * s.w;
    out4[i] = o;
}

// ---------------------------------------------------------------------------

extern "C" void kernel_launch(void* const* d_in, const int* in_sizes, int n_in,
                              void* d_out, int out_size, void* d_ws, size_t ws_size,
                              hipStream_t stream) {
    const float* x     = (const float*)d_in[0];
    const float* Wq    = (const float*)d_in[1];
    const float* bq    = (const float*)d_in[2];
    const float* Wk    = (const float*)d_in[3];
    const float* bk    = (const float*)d_in[4];
    const float* Wv    = (const float*)d_in[5];
    const float* bv    = (const float*)d_in[6];
    const float* alpha = (const float*)d_in[7];
    float* out = (float*)d_out;

    // ws layout (persistent region first — nothing here is overlaid):
    //   D         : 4096 fp32 rowsum               (16 KB)
    //   qkTh/qkTl : 4096 x 128 fp16 each           (2.0 MB)
    //   Vh/Vl     : 512 x 4096 fp16 each           (8.0 MB)
    //   Wh/Wl     : 640 x 512 fp16 each            (1.3 MB)
    //   scores    : 4096 x 4096 fp32               (67.1 MB)
    //     overlay (dead before scores written): xTh/xTl (8.4 MB)
    //   part      : (zsplit-1) x 512 x 4096 fp32   (58.7 MB at z=8)
    float* D = (float*)d_ws;
    ushort_t* qkTh = (ushort_t*)(D + HW_N);
    ushort_t* qkTl = qkTh + (size_t)HW_N * 2 * C_Q;
    ushort_t* Vh   = qkTl + (size_t)HW_N * 2 * C_Q;
    ushort_t* Vl   = Vh + (size_t)C_IN * HW_N;
    ushort_t* Wh   = Vl + (size_t)C_IN * HW_N;
    ushort_t* Wl   = Wh + (size_t)M_Y * C_IN;
    float* scores  = (float*)(Wl + (size_t)M_Y * C_IN);
    float* part    = scores + (size_t)HW_N * HW_N;

    ushort_t* xTh = (ushort_t*)scores;
    ushort_t* xTl = xTh + (size_t)HW_N * C_IN;

    // z-split: 8 needs 7 partial planes; fall back to 4 (correct, slower) if
    // the workspace can't hold them.
    const size_t planeF = (size_t)C_IN * HW_N;
    const size_t baseF  = (size_t)(part - (float*)d_ws);
    const int zsplit = (ws_size >= (baseF + 7 * planeF) * sizeof(float)) ? 8 : 4;

    split_w<<<dim3(M_Y * C_IN / 4 / 256), dim3(256), 0, stream>>>(Wq, Wk, Wv, Wh, Wl);

    for (int b = 0; b < NB; b++) {
        const float* xb = x + (size_t)b * C_IN * HW_N;
        float* outb = out + (size_t)b * C_IN * HW_N;

        split_x<<<dim3(HW_N / 64, C_IN / 64), dim3(256), 0, stream>>>(xb, xTh, xTl, D);

        // Y = W*x + b -> qkT (transposed, m<128) and V (m>=128), fp16 h/l
        ygemm<<<dim3(HW_N / 128, M_Y / 128), dim3(256), 0, stream>>>(
            Wh, Wl, xTh, xTl, bq, bk, bv, qkTh, qkTl, Vh, Vl);

        // S[i,j] = sum_c q[c,i]k[c,j]  (fp32) + fused exp-rowsum into D
        qkgemm<<<dim3(HW_N / 128, HW_N / 128), dim3(256), 0, stream>>>(
            qkTh, qkTl, scores, D);

        // res[c,i] = sum_j (Vh+Vl)[c,j] * f16(exp(S[i,j])/D[i]); z=0->out, z>0->part
        feat7<<<dim3(HW_N / 256, C_IN / 256, zsplit), dim3(512), 0, stream>>>(
            Vh, Vl, scores, D, outb, part, HW_N / zsplit);

        // out = alpha * (out + sum parts)
        reduce_alphaN<<<dim3((C_IN * HW_N / 4) / 256), dim3(256), 0, stream>>>(
            outb, (const float4*)part, (size_t)C_IN * HW_N / 4, alpha, zsplit - 1);
    }
}

// Round 6
// 467.076 us; speedup vs baseline: 1.3784x; 1.2321x over previous
//
#include <hip/hip_runtime.h>
#include <hip/hip_fp16.h>

// Problem constants (fixed by setup_inputs)
#define HW_N 4096   // 64*64 spatial positions
#define C_IN 512    // channels
#define C_Q  64     // query/key channels
#define NB   4      // batch
#define M_Y  640    // Cq + Cq + C stacked output rows
#define LOG2E 1.4426950408889634f

typedef __attribute__((ext_vector_type(8))) short short8;
typedef __attribute__((ext_vector_type(4))) short short4v;
typedef __attribute__((ext_vector_type(4))) float float4v;
typedef unsigned short ushort_t;

__device__ __forceinline__ ushort_t f2h(float x) {
    return __half_as_ushort(__float2half(x));  // RNE
}
__device__ __forceinline__ float h2f(ushort_t h) {
    return __half2float(__ushort_as_half(h));
}
__device__ __forceinline__ void gl2lds16(const ushort_t* g, ushort_t* l) {
    __builtin_amdgcn_global_load_lds(
        (const __attribute__((address_space(1))) unsigned int*)g,
        (__attribute__((address_space(3))) unsigned int*)l, 16, 0, 0);
}

// ---------------------------------------------------------------------------
// split stacked W = [Wq;Wk;Wv] (640x512 fp32) -> fp16 hi/lo (persistent region)
// ---------------------------------------------------------------------------
__global__ __launch_bounds__(256) void split_w(const float* __restrict__ Wq,
                                               const float* __restrict__ Wk,
                                               const float* __restrict__ Wv,
                                               ushort_t* __restrict__ Wh,
                                               ushort_t* __restrict__ Wl) {
    int idx = (blockIdx.x * 256 + threadIdx.x) * 4;
#pragma unroll
    for (int e = 0; e < 4; e++) {
        int i = idx + e;
        int m = i >> 9, k = i & 511;
        float v = (m < C_Q) ? Wq[m * C_IN + k]
                 : (m < 2 * C_Q) ? Wk[(m - C_Q) * C_IN + k]
                 : Wv[(size_t)(m - 2 * C_Q) * C_IN + k];
        ushort_t h = f2h(v);
        Wh[i] = h;
        Wl[i] = f2h(v - h2f(h));
    }
}

// ---------------------------------------------------------------------------
// transpose + split: x [512][4096] fp32 -> xT hi/lo [4096][512] fp16
// blockIdx.z selects the batch (round-6: one dispatch covers all batches in
// the fused path; fallback launches with z=1 and pre-offset pointers).
// Also zeroes this batch's D[4096] rowsum accumulator (y==0, x<16 blocks).
// ---------------------------------------------------------------------------
__global__ __launch_bounds__(256) void split_x(const float* __restrict__ x,
                                               ushort_t* __restrict__ xTh,
                                               ushort_t* __restrict__ xTl,
                                               float* __restrict__ D) {
    const size_t bz = blockIdx.z;
    x   += bz * ((size_t)C_IN * HW_N);
    xTh += bz * ((size_t)HW_N * C_IN);
    xTl += bz * ((size_t)HW_N * C_IN);
    D   += bz * HW_N;

    if (blockIdx.y == 0 && blockIdx.x < 16) D[blockIdx.x * 256 + threadIdx.x] = 0.f;

    __shared__ float tile[64][65];
    const int n0 = blockIdx.x * 64, k0 = blockIdx.y * 64;
    const int t = threadIdx.x;
#pragma unroll
    for (int it = 0; it < 4; it++) {
        int e = t + it * 256;
        int r = e >> 4, c4 = (e & 15) << 2;
        float4 v = *(const float4*)(x + (size_t)(k0 + r) * HW_N + n0 + c4);
        tile[r][c4 + 0] = v.x; tile[r][c4 + 1] = v.y;
        tile[r][c4 + 2] = v.z; tile[r][c4 + 3] = v.w;
    }
    __syncthreads();
    const int rr = t >> 2, kq = (t & 3) << 4;
    ushort_t h[16], l[16];
#pragma unroll
    for (int j = 0; j < 16; j++) {
        float v = tile[kq + j][rr];
        h[j] = f2h(v);
        l[j] = f2h(v - h2f(h[j]));
    }
    size_t o = (size_t)(n0 + rr) * C_IN + k0 + kq;
    *(uint4*)(xTh + o) = *(uint4*)h;
    *(uint4*)(xTh + o + 8) = *(uint4*)(h + 8);
    *(uint4*)(xTl + o) = *(uint4*)l;
    *(uint4*)(xTl + o + 8) = *(uint4*)(l + 8);
}

// ---------------------------------------------------------------------------
// Y = W*x + b GEMM: C[m,n] = sum_k A[m,k]*B[n,k], 3-term fp16 hi/lo.
// 128x128 tile, 4 waves, wave-tile 64x64.  Pipelined: double-buffered LDS,
// ONE barrier per k-step, next tile's gl2lds flies over the MFMA section.
// Pre-swizzled global column + swizzled b128 reads -> 0 bank conflicts.
// blockIdx.z = batch (W and biases shared; xT / qkT / V per-batch).
// Round-6: fused over batches -> 640 blocks (was 4 x 160 with 96 CUs idle);
// launch_bounds(256,2) for 2 blocks/CU co-residency (64 KB LDS fits 2x).
// ---------------------------------------------------------------------------
__global__ __launch_bounds__(256, 2) void ygemm(
    const ushort_t* __restrict__ Ah, const ushort_t* __restrict__ Al,
    const ushort_t* __restrict__ Bh, const ushort_t* __restrict__ Bl,
    const float* __restrict__ bq, const float* __restrict__ bk,
    const float* __restrict__ bv,
    ushort_t* __restrict__ qkTh, ushort_t* __restrict__ qkTl,
    ushort_t* __restrict__ Vh, ushort_t* __restrict__ Vl) {
    const size_t bz = blockIdx.z;
    Bh   += bz * ((size_t)HW_N * C_IN);
    Bl   += bz * ((size_t)HW_N * C_IN);
    qkTh += bz * ((size_t)HW_N * 2 * C_Q);
    qkTl += bz * ((size_t)HW_N * 2 * C_Q);
    Vh   += bz * ((size_t)C_IN * HW_N);
    Vl   += bz * ((size_t)C_IN * HW_N);

    __shared__ ushort_t sAh[2][128 * 32];
    __shared__ ushort_t sAl[2][128 * 32];
    __shared__ ushort_t sBh[2][128 * 32];
    __shared__ ushort_t sBl[2][128 * 32];

    const int tid = threadIdx.x, w = tid >> 6, lane = tid & 63;
    const int quad = lane >> 4, lr = lane & 15;
    const int m0 = blockIdx.y * 128, n0 = blockIdx.x * 128;

    // staging: wave w owns one of {Ah,Al,Bh,Bl}; 8 chunks of 16 rows.
    const ushort_t* src;
    ushort_t* dst0;
    int rowBase;
    if (w == 0)      { src = Ah; dst0 = sAh[0]; rowBase = m0; }
    else if (w == 1) { src = Al; dst0 = sAl[0]; rowBase = m0; }
    else if (w == 2) { src = Bh; dst0 = sBh[0]; rowBase = n0; }
    else             { src = Bl; dst0 = sBl[0]; rowBase = n0; }
    const int cr = lane >> 2, uv = lane & 3;
    const int kcol = (uv ^ ((cr >> 1) & 3)) << 3;   // pre-swizzled 16B k-unit
    const ushort_t* gk = src + (size_t)(rowBase + cr) * C_IN + kcol;

    const int wm = (w & 1) * 64, wn = (w >> 1) * 64;
    const int up = (quad ^ ((lr >> 1) & 3)) << 3;   // read-side swizzle

    float4v acc[4][4];
#pragma unroll
    for (int i = 0; i < 4; i++)
#pragma unroll
        for (int j = 0; j < 4; j++) acc[i][j] = (float4v){0.f, 0.f, 0.f, 0.f};

    // prologue: stage k-step 0 into buf 0
#pragma unroll
    for (int c = 0; c < 8; c++)
        gl2lds16(gk + (size_t)(c * 16) * C_IN, dst0 + c * 512);
    __syncthreads();

    const int NSTEP = C_IN / 32;    // 16
    for (int it = 0; it < NSTEP; ++it) {
        const int cur = it & 1, nxt = cur ^ 1;

        // issue next k-step's loads first — they fly over the MFMA section
        if (it + 1 < NSTEP) {
            ushort_t* db = dst0 + nxt * (128 * 32);
#pragma unroll
            for (int c = 0; c < 8; c++)
                gl2lds16(gk + (size_t)(c * 16) * C_IN + (it + 1) * 32, db + c * 512);
        }

        short8 ah[4], al[4], bh[4], bl[4];
#pragma unroll
        for (int i = 0; i < 4; i++) {
            ah[i] = *(const short8*)&sAh[cur][(wm + i * 16 + lr) * 32 + up];
            al[i] = *(const short8*)&sAl[cur][(wm + i * 16 + lr) * 32 + up];
            bh[i] = *(const short8*)&sBh[cur][(wn + i * 16 + lr) * 32 + up];
            bl[i] = *(const short8*)&sBl[cur][(wn + i * 16 + lr) * 32 + up];
        }
        // term-major order: 16 independent MFMAs between same-acc reuses
#pragma unroll
        for (int i = 0; i < 4; i++)
#pragma unroll
            for (int j = 0; j < 4; j++)
                acc[i][j] = __builtin_amdgcn_mfma_f32_16x16x32_f16(ah[i], bh[j], acc[i][j], 0, 0, 0);
#pragma unroll
        for (int i = 0; i < 4; i++)
#pragma unroll
            for (int j = 0; j < 4; j++)
                acc[i][j] = __builtin_amdgcn_mfma_f32_16x16x32_f16(ah[i], bl[j], acc[i][j], 0, 0, 0);
#pragma unroll
        for (int i = 0; i < 4; i++)
#pragma unroll
            for (int j = 0; j < 4; j++)
                acc[i][j] = __builtin_amdgcn_mfma_f32_16x16x32_f16(al[i], bh[j], acc[i][j], 0, 0, 0);
        __syncthreads();  // drains nxt's gl2lds (flew over MFMA); orders WAR
    }

    // epilogue: +bias, fp16 hi/lo split; m<128 -> qkT (transposed), else V
#pragma unroll
    for (int i = 0; i < 4; i++)
#pragma unroll
        for (int j = 0; j < 4; j++)
#pragma unroll
            for (int r = 0; r < 4; r++) {
                const int m = m0 + wm + i * 16 + quad * 4 + r;
                const int n = n0 + wn + j * 16 + lr;
                float bi = (m < C_Q) ? bq[m]
                          : (m < 2 * C_Q) ? bk[m - C_Q] : bv[m - 2 * C_Q];
                float v = acc[i][j][r] + bi;
                ushort_t h = f2h(v);
                ushort_t lo = f2h(v - h2f(h));
                if (m < 2 * C_Q) {
                    qkTh[(size_t)n * (2 * C_Q) + m] = h;
                    qkTl[(size_t)n * (2 * C_Q) + m] = lo;
                } else {
                    Vh[(size_t)(m - 2 * C_Q) * HW_N + n] = h;
                    Vl[(size_t)(m - 2 * C_Q) * HW_N + n] = lo;
                }
            }
}

// ---------------------------------------------------------------------------
// S = q^T k GEMM: S[m,n] = sum_k q[k,m]*k[k,n], 3-term fp16 hi/lo, kLen=64.
// ygemm pipeline: double-buffered 64 KB LDS (2 blocks/CU), pre-swizzled
// gl2lds staging, swizzled single-b128 fragment reads, term-major MFMA.
// Epilogue: fp32 S store + fused per-row exp-sum atomicAdd into Dsum.
// ---------------------------------------------------------------------------
__global__ __launch_bounds__(256, 2) void qkgemm(const ushort_t* __restrict__ qkTh_,
                                                 const ushort_t* __restrict__ qkTl_,
                                                 float* __restrict__ outF,
                                                 float* __restrict__ Dsum) {
    __shared__ ushort_t sAh[2][128 * 32];
    __shared__ ushort_t sAl[2][128 * 32];
    __shared__ ushort_t sBh[2][128 * 32];
    __shared__ ushort_t sBl[2][128 * 32];

    const int tid = threadIdx.x, w = tid >> 6, lane = tid & 63;
    const int quad = lane >> 4, lr = lane & 15;
    const int m0 = blockIdx.y * 128, n0 = blockIdx.x * 128;

    // staging: wave 0->q-hi, 1->q-lo, 2->k-hi, 3->k-lo; 8 chunks of 16 rows.
    const ushort_t* src = ((w & 1) ? qkTl_ : qkTh_) + ((w >> 1) ? C_Q : 0);
    ushort_t* dst0 = (w == 0) ? sAh[0] : (w == 1) ? sAl[0]
                   : (w == 2) ? sBh[0] : sBl[0];
    const int rowBase = (w >> 1) ? n0 : m0;
    const int cr = lane >> 2, uv = lane & 3;
    const int kcol = (uv ^ ((cr >> 1) & 3)) << 3;   // pre-swizzled 16B k-unit
    const ushort_t* gk = src + (size_t)(rowBase + cr) * (2 * C_Q) + kcol;

    const int wm = (w & 1) * 64, wn = (w >> 1) * 64;
    const int up = (quad ^ ((lr >> 1) & 3)) << 3;   // read-side swizzle

    float4v acc[4][4];
#pragma unroll
    for (int i = 0; i < 4; i++)
#pragma unroll
        for (int j = 0; j < 4; j++) acc[i][j] = (float4v){0.f, 0.f, 0.f, 0.f};

    // prologue: stage k-step 0 into buf 0
#pragma unroll
    for (int c = 0; c < 8; c++)
        gl2lds16(gk + (size_t)(c * 16) * (2 * C_Q), dst0 + c * 512);
    __syncthreads();

    const int NSTEP = C_Q / 32;     // 2
#pragma unroll
    for (int it = 0; it < NSTEP; ++it) {
        const int cur = it & 1, nxt = cur ^ 1;

        if (it + 1 < NSTEP) {
            ushort_t* db = dst0 + nxt * (128 * 32);
#pragma unroll
            for (int c = 0; c < 8; c++)
                gl2lds16(gk + (size_t)(c * 16) * (2 * C_Q) + (it + 1) * 32, db + c * 512);
        }

        short8 ah[4], al[4], bh[4], bl[4];
#pragma unroll
        for (int i = 0; i < 4; i++) {
            ah[i] = *(const short8*)&sAh[cur][(wm + i * 16 + lr) * 32 + up];
            al[i] = *(const short8*)&sAl[cur][(wm + i * 16 + lr) * 32 + up];
            bh[i] = *(const short8*)&sBh[cur][(wn + i * 16 + lr) * 32 + up];
            bl[i] = *(const short8*)&sBl[cur][(wn + i * 16 + lr) * 32 + up];
        }
#pragma unroll
        for (int i = 0; i < 4; i++)
#pragma unroll
            for (int j = 0; j < 4; j++)
                acc[i][j] = __builtin_amdgcn_mfma_f32_16x16x32_f16(ah[i], bh[j], acc[i][j], 0, 0, 0);
#pragma unroll
        for (int i = 0; i < 4; i++)
#pragma unroll
            for (int j = 0; j < 4; j++)
                acc[i][j] = __builtin_amdgcn_mfma_f32_16x16x32_f16(ah[i], bl[j], acc[i][j], 0, 0, 0);
#pragma unroll
        for (int i = 0; i < 4; i++)
#pragma unroll
            for (int j = 0; j < 4; j++)
                acc[i][j] = __builtin_amdgcn_mfma_f32_16x16x32_f16(al[i], bh[j], acc[i][j], 0, 0, 0);
        if (it + 1 < NSTEP) __syncthreads();  // drains nxt's gl2lds
    }

    // epilogue: store S + fused per-row exp-sum partials
#pragma unroll
    for (int i = 0; i < 4; i++) {
#pragma unroll
        for (int r = 0; r < 4; r++) {
            float s = 0.f;
#pragma unroll
            for (int j = 0; j < 4; j++) {
                const int m = m0 + wm + i * 16 + quad * 4 + r;
                const int n = n0 + wn + j * 16 + lr;
                outF[(size_t)m * HW_N + n] = acc[i][j][r];
                s += __expf(acc[i][j][r]);
            }
            s += __shfl_xor(s, 1);
            s += __shfl_xor(s, 2);
            s += __shfl_xor(s, 4);
            s += __shfl_xor(s, 8);
            if (lr == 0)
                atomicAdd(&Dsum[m0 + wm + i * 16 + quad * 4 + r], s);
        }
    }
}

// ---------------------------------------------------------------------------
// feat GEMM v4.1: res[m,n] = sum_k (Vh+Vl)[m,k] * P[n,k],
//   P[n,k] = f16( exp2(S[n,k]*log2e - log2 D[n]) )
// 256m x 256n tile, 512 threads = 8 waves (4m x 2n), wave-tile 64x128.
// Convert runs AFTER the barrier on it+1's S (2-iter prefetch distance);
// B-fragment reads before the convert so their latency hides under it.
// LDS 96 KB, 1 block/CU, grid (16,2,8); z=8 k-split partials.
// ---------------------------------------------------------------------------
__global__ __launch_bounds__(512, 2) void feat7(const ushort_t* __restrict__ Vh,
                                                const ushort_t* __restrict__ Vl,
                                                const float* __restrict__ S,
                                                const float* __restrict__ D,
                                                float* __restrict__ out,
                                                float* __restrict__ part,
                                                int kLen) {
    __shared__ ushort_t sVh[2][256 * 32];
    __shared__ ushort_t sVl[2][256 * 32];
    __shared__ ushort_t sP [2][256 * 32];

    const int tid = threadIdx.x, w = tid >> 6, lane = tid & 63;
    const int quad = lane >> 4, lr = lane & 15;
    const int m0 = blockIdx.y * 256, n0 = blockIdx.x * 256;
    const int k0 = blockIdx.z * kLen;

    // V staging: waves 0-3 -> Vh chunks (w&3)*4..+3, waves 4-7 -> Vl ditto.
    const int crv = lane >> 2, uv = lane & 3;
    const int vcol = (uv ^ ((crv >> 1) & 3)) << 3;   // swizzled 16B unit
    const ushort_t* vbase = (w < 4) ? Vh : Vl;
    const ushort_t* gVsrc[4];
    int sOfs[4];
#pragma unroll
    for (int c = 0; c < 4; c++) {
        const int chunk = ((w & 3) * 4 + c);         // 0..15 within h or l
        gVsrc[c] = vbase + (size_t)(m0 + chunk * 16 + crv) * HW_N + vcol + k0;
        sOfs[c] = chunk * 512;
    }

    // S prefetch: thread owns rows pr+64c (c=0..3), 4-float k-unit pu.
    const int pr = tid >> 3, pu = tid & 7;
    const float* gS = S + (size_t)(n0 + pr) * HW_N + k0 + pu * 4;
    const int pdst = (((pu >> 1) ^ ((pr >> 1) & 3)) << 3) + ((pu & 1) << 2);
    float lrw[4];
#pragma unroll
    for (int c = 0; c < 4; c++) lrw[c] = -log2f(D[n0 + pr + 64 * c]);

    const int wm = (w & 3) * 64, wn = (w >> 2) * 128;

    float4 sreg[4];
    const int nIter = kLen >> 5;

    // prologue: load S(0), convert -> sP[0], prefetch S(1), stage V(0)
    {
#pragma unroll
        for (int c = 0; c < 4; c++)
            sreg[c] = *(const float4*)(gS + (size_t)(64 * c) * HW_N);
#pragma unroll
        for (int c = 0; c < 4; c++) gl2lds16(gVsrc[c], ((w < 4) ? sVh : sVl)[0] + sOfs[c]);
#pragma unroll
        for (int c = 0; c < 4; c++) {
            ushort_t h4[4];
            h4[0] = f2h(exp2f(fmaf(sreg[c].x, LOG2E, lrw[c])));
            h4[1] = f2h(exp2f(fmaf(sreg[c].y, LOG2E, lrw[c])));
            h4[2] = f2h(exp2f(fmaf(sreg[c].z, LOG2E, lrw[c])));
            h4[3] = f2h(exp2f(fmaf(sreg[c].w, LOG2E, lrw[c])));
            *(short4v*)&sP[0][(pr + 64 * c) * 32 + pdst] = *(short4v*)h4;
        }
        if (nIter > 1) {
#pragma unroll
            for (int c = 0; c < 4; c++)
                sreg[c] = *(const float4*)(gS + (size_t)(64 * c) * HW_N + 32);
        }
    }
    __syncthreads();  // V(0) + sP[0] visible

    float4v acc[4][8];
#pragma unroll
    for (int i = 0; i < 4; i++)
#pragma unroll
        for (int j = 0; j < 8; j++) acc[i][j] = (float4v){0.f, 0.f, 0.f, 0.f};

    for (int it = 0; it < nIter; ++it) {
        const int kk = it << 5;
        const int cur = it & 1, nxt = cur ^ 1;

        // issue next V tile first — flies through the whole MFMA section
        if (it + 1 < nIter) {
            ushort_t* db = ((w < 4) ? sVh : sVl)[nxt];
#pragma unroll
            for (int c = 0; c < 4; c++) gl2lds16(gVsrc[c] + kk + 32, db + sOfs[c]);
        }

        // B fragments FIRST: their ds_read latency hides under the convert
        short8 bh[8];
#pragma unroll
        for (int j = 0; j < 8; j++) {
            const int row = wn + j * 16 + lr;
            bh[j] = *(const short8*)&sP[cur][row * 32 + ((quad ^ ((lr >> 1) & 3)) << 3)];
        }

        // convert S(it+1) (in regs) -> sP[nxt]; overlaps other waves' MFMA.
        if (it + 1 < nIter) {
#pragma unroll
            for (int c = 0; c < 4; c++) {
                ushort_t h4[4];
                h4[0] = f2h(exp2f(fmaf(sreg[c].x, LOG2E, lrw[c])));
                h4[1] = f2h(exp2f(fmaf(sreg[c].y, LOG2E, lrw[c])));
                h4[2] = f2h(exp2f(fmaf(sreg[c].z, LOG2E, lrw[c])));
                h4[3] = f2h(exp2f(fmaf(sreg[c].w, LOG2E, lrw[c])));
                *(short4v*)&sP[nxt][(pr + 64 * c) * 32 + pdst] = *(short4v*)h4;
            }
            if (it + 2 < nIter) {
#pragma unroll
                for (int c = 0; c < 4; c++)
                    sreg[c] = *(const float4*)(gS + (size_t)(64 * c) * HW_N + kk + 64);
            }
        }

#pragma unroll
        for (int i = 0; i < 4; i++) {
            const int row = wm + i * 16 + lr;
            const int up = (quad ^ ((lr >> 1) & 3)) << 3;
            short8 ah = *(const short8*)&sVh[cur][row * 32 + up];
            short8 al = *(const short8*)&sVl[cur][row * 32 + up];
#pragma unroll
            for (int j = 0; j < 8; j++)
                acc[i][j] = __builtin_amdgcn_mfma_f32_16x16x32_f16(ah, bh[j], acc[i][j], 0, 0, 0);
#pragma unroll
            for (int j = 0; j < 8; j++)
                acc[i][j] = __builtin_amdgcn_mfma_f32_16x16x32_f16(al, bh[j], acc[i][j], 0, 0, 0);
        }
        __syncthreads();  // drains: vbuf[nxt] gl2lds, sP[nxt] writes; orders WAR
    }

    float* o = (blockIdx.z == 0) ? out
             : (part + (size_t)(blockIdx.z - 1) * ((size_t)C_IN * HW_N));
#pragma unroll
    for (int i = 0; i < 4; i++)
#pragma unroll
        for (int j = 0; j < 8; j++)
#pragma unroll
            for (int r = 0; r < 4; r++) {
                const int m = m0 + wm + i * 16 + quad * 4 + r;
                const int n = n0 + wn + j * 16 + lr;
                o[(size_t)m * HW_N + n] = acc[i][j][r];
            }
}

// out = alpha * (out + sum of np partials), float4-vectorized
__global__ __launch_bounds__(256) void reduce_alphaN(float* __restrict__ out,
                                                     const float4* __restrict__ part,
                                                     size_t stride4,
                                                     const float* __restrict__ alpha,
                                                     int np) {
    const size_t i = (size_t)blockIdx.x * 256 + threadIdx.x;
    const float a = alpha[0];
    float4* out4 = (float4*)out;
    float4 s = out4[i];
    for (int p = 0; p < np; p++) {
        float4 t = part[i + (size_t)p * stride4];
        s.x += t.x; s.y += t.y; s.z += t.z; s.w += t.w;
    }
    float4 o;
    o.x = a * s.x; o.y = a * s.y; o.z = a * s.z; o.w = a * s.w;
    out4[i] = o;
}

// ---------------------------------------------------------------------------

extern "C" void kernel_launch(void* const* d_in, const int* in_sizes, int n_in,
                              void* d_out, int out_size, void* d_ws, size_t ws_size,
                              hipStream_t stream) {
    const float* x     = (const float*)d_in[0];
    const float* Wq    = (const float*)d_in[1];
    const float* bq    = (const float*)d_in[2];
    const float* Wk    = (const float*)d_in[3];
    const float* bk    = (const float*)d_in[4];
    const float* Wv    = (const float*)d_in[5];
    const float* bv    = (const float*)d_in[6];
    const float* alpha = (const float*)d_in[7];
    float* out = (float*)d_out;

    const size_t planeQK = (size_t)HW_N * 2 * C_Q;   // qkT elems / batch
    const size_t planeV  = (size_t)C_IN * HW_N;      // V (and out) elems / batch
    const size_t planeXT = (size_t)HW_N * C_IN;      // xT elems / batch
    const size_t planeW  = (size_t)M_Y * C_IN;
    const size_t planeS  = (size_t)HW_N * HW_N;

    // --- fused (4-batch) layout -------------------------------------------
    //   D4    : 4 x 4096 fp32
    //   qkTh4/qkTl4 : 4 x planeQK fp16 each        (8.4 MB)
    //   Vh4/Vl4     : 4 x planeV fp16 each         (33.6 MB)
    //   Wh/Wl       : planeW fp16 each             (1.3 MB)
    //   scores      : planeS fp32                  (67.1 MB)
    //     overlay (dead after ygemm): xTh4/xTl4    (33.6 MB <= 67.1 OK)
    //   part        : 7 x planeV fp32              (58.7 MB)
    // total ~169.2 MB.  Fallback (per-batch) layout ~137.7 MB.
    const size_t fusedBytes =
        (size_t)NB * HW_N * 4 + 2 * (size_t)NB * planeQK * 2 +
        2 * (size_t)NB * planeV * 2 + 2 * planeW * 2 + planeS * 4 +
        7 * planeV * 4;
    const bool fused = (ws_size >= fusedBytes);

    if (fused) {
        float* D4      = (float*)d_ws;
        ushort_t* qkTh4 = (ushort_t*)(D4 + (size_t)NB * HW_N);
        ushort_t* qkTl4 = qkTh4 + (size_t)NB * planeQK;
        ushort_t* Vh4   = qkTl4 + (size_t)NB * planeQK;
        ushort_t* Vl4   = Vh4 + (size_t)NB * planeV;
        ushort_t* Wh    = Vl4 + (size_t)NB * planeV;
        ushort_t* Wl    = Wh + planeW;
        float* scores   = (float*)(Wl + planeW);
        float* part     = scores + planeS;
        ushort_t* xTh4  = (ushort_t*)scores;           // overlay
        ushort_t* xTl4  = xTh4 + (size_t)NB * planeXT;

        split_w<<<dim3(M_Y * C_IN / 4 / 256), dim3(256), 0, stream>>>(Wq, Wk, Wv, Wh, Wl);

        // all 4 batches in one dispatch each
        split_x<<<dim3(HW_N / 64, C_IN / 64, NB), dim3(256), 0, stream>>>(
            x, xTh4, xTl4, D4);
        ygemm<<<dim3(HW_N / 128, M_Y / 128, NB), dim3(256), 0, stream>>>(
            Wh, Wl, xTh4, xTl4, bq, bk, bv, qkTh4, qkTl4, Vh4, Vl4);
        // (xT region dead from here on; scores may overwrite it)

        for (int b = 0; b < NB; b++) {
            float* outb = out + (size_t)b * planeV;
            qkgemm<<<dim3(HW_N / 128, HW_N / 128), dim3(256), 0, stream>>>(
                qkTh4 + (size_t)b * planeQK, qkTl4 + (size_t)b * planeQK,
                scores, D4 + (size_t)b * HW_N);
            feat7<<<dim3(HW_N / 256, C_IN / 256, 8), dim3(512), 0, stream>>>(
                Vh4 + (size_t)b * planeV, Vl4 + (size_t)b * planeV,
                scores, D4 + (size_t)b * HW_N, outb, part, HW_N / 8);
            reduce_alphaN<<<dim3((C_IN * HW_N / 4) / 256), dim3(256), 0, stream>>>(
                outb, (const float4*)part, planeV / 4, alpha, 7);
        }
        return;
    }

    // --- fallback: per-batch layout + loop (round-5 behavior) -------------
    float* D = (float*)d_ws;
    ushort_t* qkTh = (ushort_t*)(D + HW_N);
    ushort_t* qkTl = qkTh + planeQK;
    ushort_t* Vh   = qkTl + planeQK;
    ushort_t* Vl   = Vh + planeV;
    ushort_t* Wh   = Vl + planeV;
    ushort_t* Wl   = Wh + planeW;
    float* scores  = (float*)(Wl + planeW);
    float* part    = scores + planeS;
    ushort_t* xTh  = (ushort_t*)scores;
    ushort_t* xTl  = xTh + planeXT;

    const size_t baseF = (size_t)(part - (float*)d_ws);
    const int zsplit = (ws_size >= (baseF + 7 * planeV) * sizeof(float)) ? 8 : 4;

    split_w<<<dim3(M_Y * C_IN / 4 / 256), dim3(256), 0, stream>>>(Wq, Wk, Wv, Wh, Wl);

    for (int b = 0; b < NB; b++) {
        const float* xb = x + (size_t)b * planeV;
        float* outb = out + (size_t)b * planeV;

        split_x<<<dim3(HW_N / 64, C_IN / 64, 1), dim3(256), 0, stream>>>(
            xb, xTh, xTl, D);
        ygemm<<<dim3(HW_N / 128, M_Y / 128, 1), dim3(256), 0, stream>>>(
            Wh, Wl, xTh, xTl, bq, bk, bv, qkTh, qkTl, Vh, Vl);
        qkgemm<<<dim3(HW_N / 128, HW_N / 128), dim3(256), 0, stream>>>(
            qkTh, qkTl, scores, D);
        feat7<<<dim3(HW_N / 256, C_IN / 256, zsplit), dim3(512), 0, stream>>>(
            Vh, Vl, scores, D, outb, part, HW_N / zsplit);
        reduce_alphaN<<<dim3((C_IN * HW_N / 4) / 256), dim3(256), 0, stream>>>(
            outb, (const float4*)part, planeV / 4, alpha, zsplit - 1);
    }
}